// Round 1
// baseline (507.456 us; speedup 1.0000x reference)
//
#include <hip/hip_runtime.h>

#define IN_F 256
#define OUT_F 128
#define ALPHA 0.2f
#define EPS 9e-15f

// ---------------- K1: h = input @ W  (N x 256) @ (256 x 128) f32 ----------------
// 128x128 output tile per block, K-chunks of 64, 8x8 outputs per thread.
__global__ __launch_bounds__(256) void k_gemm(const float* __restrict__ input,
                                              const float* __restrict__ W,
                                              float* __restrict__ h, int n) {
    __shared__ float Wt[64][128];   // Wt[kk][j]
    __shared__ float It[64][128];   // It[kk][r]  (transposed input tile)
    const int t = threadIdx.x;
    const int row0 = blockIdx.x * 128;
    const int tx = t & 15;          // col group: cols tx*8 .. +7
    const int ty = t >> 4;          // row group: rows ty*8 .. +7

    float acc[8][8];
#pragma unroll
    for (int r = 0; r < 8; ++r)
#pragma unroll
        for (int c = 0; c < 8; ++c) acc[r][c] = 0.f;

    for (int k0 = 0; k0 < IN_F; k0 += 64) {
        // stage W chunk: 64 x 128 floats = 2048 float4
#pragma unroll
        for (int i = 0; i < 8; ++i) {
            int fidx = i * 256 + t;
            int wr = fidx >> 5, wc4 = fidx & 31;
            float4 v = *(const float4*)&W[(k0 + wr) * OUT_F + wc4 * 4];
            *(float4*)&Wt[wr][wc4 * 4] = v;
        }
        // stage input chunk transposed: rows row0..row0+127, k = k0..k0+63
#pragma unroll
        for (int i = 0; i < 8; ++i) {
            int fidx = i * 256 + t;
            int rr = fidx >> 4, c4 = fidx & 15;
            int grow = row0 + rr;
            float4 v = make_float4(0.f, 0.f, 0.f, 0.f);
            if (grow < n) v = *(const float4*)&input[grow * IN_F + k0 + c4 * 4];
            It[c4 * 4 + 0][rr] = v.x;
            It[c4 * 4 + 1][rr] = v.y;
            It[c4 * 4 + 2][rr] = v.z;
            It[c4 * 4 + 3][rr] = v.w;
        }
        __syncthreads();
#pragma unroll 8
        for (int kk = 0; kk < 64; ++kk) {
            float4 w0 = *(float4*)&Wt[kk][tx * 8];
            float4 w1 = *(float4*)&Wt[kk][tx * 8 + 4];
            float4 i0 = *(float4*)&It[kk][ty * 8];
            float4 i1 = *(float4*)&It[kk][ty * 8 + 4];
            float wv[8] = {w0.x, w0.y, w0.z, w0.w, w1.x, w1.y, w1.z, w1.w};
            float iv[8] = {i0.x, i0.y, i0.z, i0.w, i1.x, i1.y, i1.z, i1.w};
#pragma unroll
            for (int r = 0; r < 8; ++r)
#pragma unroll
                for (int c = 0; c < 8; ++c)
                    acc[r][c] = fmaf(iv[r], wv[c], acc[r][c]);
        }
        __syncthreads();
    }
    // store
#pragma unroll
    for (int r = 0; r < 8; ++r) {
        int grow = row0 + ty * 8 + r;
        if (grow < n) {
            float4 o0 = make_float4(acc[r][0], acc[r][1], acc[r][2], acc[r][3]);
            float4 o1 = make_float4(acc[r][4], acc[r][5], acc[r][6], acc[r][7]);
            *(float4*)&h[grow * OUT_F + tx * 8] = o0;
            *(float4*)&h[grow * OUT_F + tx * 8 + 4] = o1;
        }
    }
}

// ---------------- K1b: hs[i] = h[i] . a_src, hd[i] = h[i] . a_dst ----------------
__global__ __launch_bounds__(256) void k_hsd(const float* __restrict__ h,
                                             const float* __restrict__ a,
                                             float* __restrict__ hs,
                                             float* __restrict__ hd, int n) {
    int wid = threadIdx.x >> 6, lane = threadIdx.x & 63;
    int node = blockIdx.x * 4 + wid;
    if (node >= n) return;
    float h0 = h[node * OUT_F + lane];
    float h1 = h[node * OUT_F + 64 + lane];
    float s = h0 * a[lane] + h1 * a[64 + lane];
    float d = h0 * a[128 + lane] + h1 * a[192 + lane];
#pragma unroll
    for (int o = 32; o; o >>= 1) {
        s += __shfl_xor(s, o);
        d += __shfl_xor(d, o);
    }
    if (lane == 0) { hs[node] = s; hd[node] = d; }
}

// ---------------- war = Wr @ a_r  (8-vector) ----------------
__global__ void k_war(const float* __restrict__ Wr, const float* __restrict__ a,
                      float* __restrict__ war) {
    int t = threadIdx.x;
    if (t < 8) {
        float s = 0.f;
        for (int j = 0; j < OUT_F; ++j) s += Wr[t * OUT_F + j] * a[2 * OUT_F + j];
        war[t] = s;
    }
}

// ---------------- K2: per-edge score -> edge_e, plus src histogram ----------------
__global__ __launch_bounds__(256) void k_edge(const int* __restrict__ ei,
                                              const float* __restrict__ ew,
                                              const float* __restrict__ er,
                                              const float* __restrict__ hs,
                                              const float* __restrict__ hd,
                                              const float* __restrict__ war,
                                              const float* __restrict__ a,
                                              float* __restrict__ edge_e,
                                              int* __restrict__ cnt,
                                              int nE, int n) {
    int e = blockIdx.x * 256 + threadIdx.x;
    if (e >= nE) return;
    int s = ei[e], d = ei[nE + e];
    s = min(max(s, 0), n - 1);
    d = min(max(d, 0), n - 1);
    float4 r0 = *(const float4*)&er[e * 8];
    float4 r1 = *(const float4*)&er[e * 8 + 4];
    float sc = hs[s] + hd[d]
             + r0.x * war[0] + r0.y * war[1] + r0.z * war[2] + r0.w * war[3]
             + r1.x * war[4] + r1.y * war[5] + r1.z * war[6] + r1.w * war[7]
             + a[3 * OUT_F] * ew[e];
    float lr = sc > 0.f ? sc : ALPHA * sc;
    edge_e[e] = expf(-lr);
    atomicAdd(&cnt[s], 1);
}

// ---------------- K3: exclusive scan of cnt -> offsets ----------------
__global__ __launch_bounds__(256) void k_scan1(const int* __restrict__ cnt,
                                               int* __restrict__ offs,
                                               int* __restrict__ bsum, int n) {
    __shared__ int sA[512], sB[512];
    int t = threadIdx.x;
    int base = blockIdx.x * 512;
    sA[t] = (base + t < n) ? cnt[base + t] : 0;
    sA[t + 256] = (base + 256 + t < n) ? cnt[base + 256 + t] : 0;
    __syncthreads();
    int* src = sA;
    int* dst = sB;
    for (int ofs = 1; ofs < 512; ofs <<= 1) {
        dst[t] = src[t] + (t >= ofs ? src[t - ofs] : 0);
        int i1 = t + 256;
        dst[i1] = src[i1] + (i1 >= ofs ? src[i1 - ofs] : 0);
        __syncthreads();
        int* tmp = src; src = dst; dst = tmp;
    }
    // src now holds inclusive scan of 512 elements
    if (base + t < n) offs[base + t] = t ? src[t - 1] : 0;
    if (base + 256 + t < n) offs[base + 256 + t] = src[t + 255];
    if (t == 0) bsum[blockIdx.x] = src[511];
}

__global__ void k_scan2(const int* __restrict__ bsum, int* __restrict__ boffs,
                        int nb, int* __restrict__ offs, int n, int nE) {
    if (threadIdx.x == 0 && blockIdx.x == 0) {
        int run = 0;
        for (int i = 0; i < nb; ++i) { boffs[i] = run; run += bsum[i]; }
        offs[n] = nE;
    }
}

__global__ __launch_bounds__(256) void k_scan3(int* __restrict__ offs,
                                               const int* __restrict__ boffs, int n) {
    int i = blockIdx.x * 256 + threadIdx.x;
    if (i < n) offs[i] += boffs[i >> 9];
}

// ---------------- K4: scatter edge ids sorted by src ----------------
__global__ __launch_bounds__(256) void k_scatter(const int* __restrict__ ei,
                                                 const int* __restrict__ offs,
                                                 int* __restrict__ cursor,
                                                 int* __restrict__ sorted,
                                                 int nE, int n) {
    int e = blockIdx.x * 256 + threadIdx.x;
    if (e >= nE) return;
    int s = ei[e];
    s = min(max(s, 0), n - 1);
    int pos = offs[s] + atomicAdd(&cursor[s], 1);
    sorted[pos] = e;
}

// ---------------- K5: per-node accumulation + finalize (elu) ----------------
__global__ __launch_bounds__(256) void k_acc(const int* __restrict__ ei,
                                             const float* __restrict__ edge_e,
                                             const int* __restrict__ offs,
                                             const int* __restrict__ sorted,
                                             const float* __restrict__ h,
                                             float* __restrict__ out,
                                             int n, int nE) {
    int wid = threadIdx.x >> 6, lane = threadIdx.x & 63;
    int node = blockIdx.x * 4 + wid;
    if (node >= n) return;
    int beg = offs[node], end = offs[node + 1];
    float ax = 0.f, ay = 0.f, rowsum = 0.f;
    for (int idx = beg; idx < end; ++idx) {
        int e = sorted[idx];
        int d = ei[nE + e];
        d = min(max(d, 0), n - 1);
        float ee = edge_e[e];
        float2 hv = *(const float2*)&h[d * OUT_F + lane * 2];
        ax = fmaf(ee, hv.x, ax);
        ay = fmaf(ee, hv.y, ay);
        rowsum += ee;
    }
    float inv = 1.f / (rowsum + EPS);
    float x = ax * inv, y = ay * inv;
    x = x > 0.f ? x : (expf(x) - 1.f);
    y = y > 0.f ? y : (expf(y) - 1.f);
    float2 o = make_float2(x, y);
    *(float2*)&out[node * OUT_F + lane * 2] = o;
}

static inline size_t align_up(size_t v, size_t al) { return (v + al - 1) & ~(al - 1); }

extern "C" void kernel_launch(void* const* d_in, const int* in_sizes, int n_in,
                              void* d_out, int out_size, void* d_ws, size_t ws_size,
                              hipStream_t stream) {
    const float* input = (const float*)d_in[0];
    const int*   ei    = (const int*)d_in[1];
    const float* ew    = (const float*)d_in[2];
    const float* er    = (const float*)d_in[3];
    const float* W     = (const float*)d_in[4];
    const float* Wr    = (const float*)d_in[5];
    const float* a     = (const float*)d_in[6];
    float* out = (float*)d_out;

    const int n  = in_sizes[0] / IN_F;   // 50000
    const int nE = in_sizes[2];          // 1600000

    // workspace carve (bytes)
    char* p = (char*)d_ws;
    size_t o = 0;
    float* h      = (float*)(p + o); o = align_up(o + (size_t)n * OUT_F * 4, 256);
    float* hs     = (float*)(p + o); o = align_up(o + (size_t)n * 4, 256);
    float* hd     = (float*)(p + o); o = align_up(o + (size_t)n * 4, 256);
    float* war    = (float*)(p + o); o = align_up(o + 8 * 4, 256);
    float* edge_e = (float*)(p + o); o = align_up(o + (size_t)nE * 4, 256);
    int*   cnt    = (int*)(p + o);   o = align_up(o + (size_t)n * 4, 256);
    int*   offs   = (int*)(p + o);   o = align_up(o + (size_t)(n + 1) * 4, 256);
    int*   cursor = (int*)(p + o);   o = align_up(o + (size_t)n * 4, 256);
    int*   sorted = (int*)(p + o);   o = align_up(o + (size_t)nE * 4, 256);
    int*   bsum   = (int*)(p + o);   o = align_up(o + 4096, 256);
    int*   boffs  = (int*)(p + o);   o = align_up(o + 4096, 256);
    (void)ws_size; (void)n_in; (void)out_size;

    hipMemsetAsync(cnt, 0, (size_t)n * 4, stream);
    hipMemsetAsync(cursor, 0, (size_t)n * 4, stream);

    k_gemm<<<(n + 127) / 128, 256, 0, stream>>>(input, W, h, n);
    k_war<<<1, 64, 0, stream>>>(Wr, a, war);
    k_hsd<<<(n + 3) / 4, 256, 0, stream>>>(h, a, hs, hd, n);
    k_edge<<<(nE + 255) / 256, 256, 0, stream>>>(ei, ew, er, hs, hd, war, a,
                                                 edge_e, cnt, nE, n);
    int nb = (n + 511) / 512;
    k_scan1<<<nb, 256, 0, stream>>>(cnt, offs, bsum, n);
    k_scan2<<<1, 64, 0, stream>>>(bsum, boffs, nb, offs, n, nE);
    k_scan3<<<(n + 255) / 256, 256, 0, stream>>>(offs, boffs, n);
    k_scatter<<<(nE + 255) / 256, 256, 0, stream>>>(ei, offs, cursor, sorted, nE, n);
    k_acc<<<(n + 3) / 4, 256, 0, stream>>>(ei, edge_e, offs, sorted, h, out, n, nE);
}

// Round 2
// 372.882 us; speedup vs baseline: 1.3609x; 1.3609x over previous
//
#include <hip/hip_runtime.h>

#define IN_F 256
#define OUT_F 128
#define ALPHA 0.2f
#define EPS 9e-15f

// ---------------- K1: h = input @ W  (N x 256) @ (256 x 128) f32 ----------------
// 128x128 output tile per block, K-chunks of 64, 8x8 outputs per thread.
// Epilogue also computes hs = h.a_src, hd = h.a_dst per row (fused).
__global__ __launch_bounds__(256) void k_gemm(const float* __restrict__ input,
                                              const float* __restrict__ W,
                                              const float* __restrict__ a,
                                              float* __restrict__ h,
                                              float* __restrict__ hs,
                                              float* __restrict__ hd, int n) {
    __shared__ float Wt[64][128];   // Wt[kk][j]
    __shared__ float It[64][128];   // It[kk][r]  (transposed input tile)
    const int t = threadIdx.x;
    const int row0 = blockIdx.x * 128;
    const int tx = t & 15;          // col group: cols tx*8 .. +7
    const int ty = t >> 4;          // row group: rows ty*8 .. +7

    float acc[8][8];
#pragma unroll
    for (int r = 0; r < 8; ++r)
#pragma unroll
        for (int c = 0; c < 8; ++c) acc[r][c] = 0.f;

    for (int k0 = 0; k0 < IN_F; k0 += 64) {
        // stage W chunk: 64 x 128 floats = 2048 float4
#pragma unroll
        for (int i = 0; i < 8; ++i) {
            int fidx = i * 256 + t;
            int wr = fidx >> 5, wc4 = fidx & 31;
            float4 v = *(const float4*)&W[(k0 + wr) * OUT_F + wc4 * 4];
            *(float4*)&Wt[wr][wc4 * 4] = v;
        }
        // stage input chunk transposed: rows row0..row0+127, k = k0..k0+63
#pragma unroll
        for (int i = 0; i < 8; ++i) {
            int fidx = i * 256 + t;
            int rr = fidx >> 4, c4 = fidx & 15;
            int grow = row0 + rr;
            float4 v = make_float4(0.f, 0.f, 0.f, 0.f);
            if (grow < n) v = *(const float4*)&input[grow * IN_F + k0 + c4 * 4];
            It[c4 * 4 + 0][rr] = v.x;
            It[c4 * 4 + 1][rr] = v.y;
            It[c4 * 4 + 2][rr] = v.z;
            It[c4 * 4 + 3][rr] = v.w;
        }
        __syncthreads();
#pragma unroll 8
        for (int kk = 0; kk < 64; ++kk) {
            float4 w0 = *(float4*)&Wt[kk][tx * 8];
            float4 w1 = *(float4*)&Wt[kk][tx * 8 + 4];
            float4 i0 = *(float4*)&It[kk][ty * 8];
            float4 i1 = *(float4*)&It[kk][ty * 8 + 4];
            float wv[8] = {w0.x, w0.y, w0.z, w0.w, w1.x, w1.y, w1.z, w1.w};
            float iv[8] = {i0.x, i0.y, i0.z, i0.w, i1.x, i1.y, i1.z, i1.w};
#pragma unroll
            for (int r = 0; r < 8; ++r)
#pragma unroll
                for (int c = 0; c < 8; ++c)
                    acc[r][c] = fmaf(iv[r], wv[c], acc[r][c]);
        }
        __syncthreads();
    }

    // load a_src/a_dst slices for this thread's 8 columns
    float as[8], ad[8];
#pragma unroll
    for (int c = 0; c < 8; ++c) {
        as[c] = a[tx * 8 + c];
        ad[c] = a[OUT_F + tx * 8 + c];
    }

    // store h + fused per-row dots
#pragma unroll
    for (int r = 0; r < 8; ++r) {
        int grow = row0 + ty * 8 + r;
        float ps = 0.f, pd = 0.f;
#pragma unroll
        for (int c = 0; c < 8; ++c) {
            ps = fmaf(acc[r][c], as[c], ps);
            pd = fmaf(acc[r][c], ad[c], pd);
        }
        // reduce across the 16 tx-lanes (contiguous lanes within the wave)
#pragma unroll
        for (int o = 8; o; o >>= 1) {
            ps += __shfl_xor(ps, o);
            pd += __shfl_xor(pd, o);
        }
        if (grow < n) {
            float4 o0 = make_float4(acc[r][0], acc[r][1], acc[r][2], acc[r][3]);
            float4 o1 = make_float4(acc[r][4], acc[r][5], acc[r][6], acc[r][7]);
            *(float4*)&h[grow * OUT_F + tx * 8] = o0;
            *(float4*)&h[grow * OUT_F + tx * 8 + 4] = o1;
            if (tx == 0) { hs[grow] = ps; hd[grow] = pd; }
        }
    }
}

// ---------------- K2: per-edge score -> edge_e, plus src histogram ----------------
// war = Wr @ a_r computed per-block into LDS (1K FLOP, L2-resident operands).
__global__ __launch_bounds__(256) void k_edge(const int* __restrict__ ei,
                                              const float* __restrict__ ew,
                                              const float* __restrict__ er,
                                              const float* __restrict__ hs,
                                              const float* __restrict__ hd,
                                              const float* __restrict__ Wr,
                                              const float* __restrict__ a,
                                              float* __restrict__ edge_e,
                                              int* __restrict__ cnt,
                                              int nE, int n) {
    __shared__ float war[8];
    {
        int t = threadIdx.x;
        int rr = t >> 5;          // 0..7
        int l5 = t & 31;          // lane within group of 32
        float p = 0.f;
#pragma unroll
        for (int k = 0; k < 4; ++k)
            p = fmaf(Wr[rr * OUT_F + l5 * 4 + k], a[2 * OUT_F + l5 * 4 + k], p);
#pragma unroll
        for (int o = 16; o; o >>= 1) p += __shfl_xor(p, o, 32);
        if (l5 == 0) war[rr] = p;
    }
    __syncthreads();

    int e = blockIdx.x * 256 + threadIdx.x;
    if (e >= nE) return;
    int s = ei[e], d = ei[nE + e];
    s = min(max(s, 0), n - 1);
    d = min(max(d, 0), n - 1);
    float4 r0 = *(const float4*)&er[e * 8];
    float4 r1 = *(const float4*)&er[e * 8 + 4];
    float sc = hs[s] + hd[d]
             + r0.x * war[0] + r0.y * war[1] + r0.z * war[2] + r0.w * war[3]
             + r1.x * war[4] + r1.y * war[5] + r1.z * war[6] + r1.w * war[7]
             + a[3 * OUT_F] * ew[e];
    float lr = sc > 0.f ? sc : ALPHA * sc;
    edge_e[e] = expf(-lr);
    atomicAdd(&cnt[s], 1);
}

// ---------------- K3: exclusive scan of cnt -> offsets ----------------
__global__ __launch_bounds__(256) void k_scan1(const int* __restrict__ cnt,
                                               int* __restrict__ offs,
                                               int* __restrict__ bsum, int n) {
    __shared__ int sA[512], sB[512];
    int t = threadIdx.x;
    int base = blockIdx.x * 512;
    sA[t] = (base + t < n) ? cnt[base + t] : 0;
    sA[t + 256] = (base + 256 + t < n) ? cnt[base + 256 + t] : 0;
    __syncthreads();
    int* src = sA;
    int* dst = sB;
    for (int ofs = 1; ofs < 512; ofs <<= 1) {
        dst[t] = src[t] + (t >= ofs ? src[t - ofs] : 0);
        int i1 = t + 256;
        dst[i1] = src[i1] + (i1 >= ofs ? src[i1 - ofs] : 0);
        __syncthreads();
        int* tmp = src; src = dst; dst = tmp;
    }
    if (base + t < n) offs[base + t] = t ? src[t - 1] : 0;
    if (base + 256 + t < n) offs[base + 256 + t] = src[t + 255];
    if (t == 0) bsum[blockIdx.x] = src[511];
}

__global__ void k_scan2(const int* __restrict__ bsum, int* __restrict__ boffs,
                        int nb, int* __restrict__ offs, int n, int nE) {
    if (threadIdx.x == 0 && blockIdx.x == 0) {
        int run = 0;
        for (int i = 0; i < nb; ++i) { boffs[i] = run; run += bsum[i]; }
        offs[n] = nE;
    }
}

__global__ __launch_bounds__(256) void k_scan3(int* __restrict__ offs,
                                               const int* __restrict__ boffs, int n) {
    int i = blockIdx.x * 256 + threadIdx.x;
    if (i < n) offs[i] += boffs[i >> 9];
}

// ---------------- K4: scatter (dst, ee) pairs sorted by src ----------------
__global__ __launch_bounds__(256) void k_scatter(const int* __restrict__ ei,
                                                 const float* __restrict__ edge_e,
                                                 const int* __restrict__ offs,
                                                 int* __restrict__ cursor,
                                                 int2* __restrict__ pairs,
                                                 int nE, int n) {
    int e = blockIdx.x * 256 + threadIdx.x;
    if (e >= nE) return;
    int s = ei[e];
    int d = ei[nE + e];
    s = min(max(s, 0), n - 1);
    d = min(max(d, 0), n - 1);
    int pos = offs[s] + atomicAdd(&cursor[s], 1);
    int2 pr;
    pr.x = d;
    pr.y = __float_as_int(edge_e[e]);
    pairs[pos] = pr;
}

// ---------------- K5: per-node accumulation + finalize (elu) ----------------
__global__ __launch_bounds__(256) void k_acc(const int2* __restrict__ pairs,
                                             const int* __restrict__ offs,
                                             const float* __restrict__ h,
                                             float* __restrict__ out, int n) {
    int wid = threadIdx.x >> 6, lane = threadIdx.x & 63;
    int node = blockIdx.x * 4 + wid;
    if (node >= n) return;
    int beg = offs[node], end = offs[node + 1];
    float ax = 0.f, ay = 0.f, rowsum = 0.f;
    int idx = beg;
    for (; idx + 4 <= end; idx += 4) {
        int2 p0 = pairs[idx];
        int2 p1 = pairs[idx + 1];
        int2 p2 = pairs[idx + 2];
        int2 p3 = pairs[idx + 3];
        float2 h0 = *(const float2*)&h[(size_t)p0.x * OUT_F + lane * 2];
        float2 h1 = *(const float2*)&h[(size_t)p1.x * OUT_F + lane * 2];
        float2 h2 = *(const float2*)&h[(size_t)p2.x * OUT_F + lane * 2];
        float2 h3 = *(const float2*)&h[(size_t)p3.x * OUT_F + lane * 2];
        float e0 = __int_as_float(p0.y);
        float e1 = __int_as_float(p1.y);
        float e2 = __int_as_float(p2.y);
        float e3 = __int_as_float(p3.y);
        ax = fmaf(e0, h0.x, ax); ay = fmaf(e0, h0.y, ay);
        ax = fmaf(e1, h1.x, ax); ay = fmaf(e1, h1.y, ay);
        ax = fmaf(e2, h2.x, ax); ay = fmaf(e2, h2.y, ay);
        ax = fmaf(e3, h3.x, ax); ay = fmaf(e3, h3.y, ay);
        rowsum += (e0 + e1) + (e2 + e3);
    }
    for (; idx < end; ++idx) {
        int2 p = pairs[idx];
        float ee = __int_as_float(p.y);
        float2 hv = *(const float2*)&h[(size_t)p.x * OUT_F + lane * 2];
        ax = fmaf(ee, hv.x, ax);
        ay = fmaf(ee, hv.y, ay);
        rowsum += ee;
    }
    float inv = 1.f / (rowsum + EPS);
    float x = ax * inv, y = ay * inv;
    x = x > 0.f ? x : (expf(x) - 1.f);
    y = y > 0.f ? y : (expf(y) - 1.f);
    float2 o = make_float2(x, y);
    *(float2*)&out[node * OUT_F + lane * 2] = o;
}

static inline size_t align_up(size_t v, size_t al) { return (v + al - 1) & ~(al - 1); }

extern "C" void kernel_launch(void* const* d_in, const int* in_sizes, int n_in,
                              void* d_out, int out_size, void* d_ws, size_t ws_size,
                              hipStream_t stream) {
    const float* input = (const float*)d_in[0];
    const int*   ei    = (const int*)d_in[1];
    const float* ew    = (const float*)d_in[2];
    const float* er    = (const float*)d_in[3];
    const float* W     = (const float*)d_in[4];
    const float* Wr    = (const float*)d_in[5];
    const float* a     = (const float*)d_in[6];
    float* out = (float*)d_out;

    const int n  = in_sizes[0] / IN_F;   // 50000
    const int nE = in_sizes[2];          // 1600000

    // workspace carve (bytes)
    char* p = (char*)d_ws;
    size_t o = 0;
    float* h      = (float*)(p + o); o = align_up(o + (size_t)n * OUT_F * 4, 256);
    float* hs     = (float*)(p + o); o = align_up(o + (size_t)n * 4, 256);
    float* hd     = (float*)(p + o); o = align_up(o + (size_t)n * 4, 256);
    float* edge_e = (float*)(p + o); o = align_up(o + (size_t)nE * 4, 256);
    int*   cnt    = (int*)(p + o);   o = align_up(o + (size_t)n * 4, 256);
    int*   offs   = (int*)(p + o);   o = align_up(o + (size_t)(n + 1) * 4, 256);
    int*   cursor = (int*)(p + o);   o = align_up(o + (size_t)n * 4, 256);
    int2*  pairs  = (int2*)(p + o);  o = align_up(o + (size_t)nE * 8, 256);
    int*   bsum   = (int*)(p + o);   o = align_up(o + 4096, 256);
    int*   boffs  = (int*)(p + o);   o = align_up(o + 4096, 256);
    (void)ws_size; (void)n_in; (void)out_size;

    hipMemsetAsync(cnt, 0, (size_t)n * 4, stream);
    hipMemsetAsync(cursor, 0, (size_t)n * 4, stream);

    k_gemm<<<(n + 127) / 128, 256, 0, stream>>>(input, W, a, h, hs, hd, n);
    k_edge<<<(nE + 255) / 256, 256, 0, stream>>>(ei, ew, er, hs, hd, Wr, a,
                                                 edge_e, cnt, nE, n);
    int nb = (n + 511) / 512;
    k_scan1<<<nb, 256, 0, stream>>>(cnt, offs, bsum, n);
    k_scan2<<<1, 64, 0, stream>>>(bsum, boffs, nb, offs, n, nE);
    k_scan3<<<(n + 255) / 256, 256, 0, stream>>>(offs, boffs, n);
    k_scatter<<<(nE + 255) / 256, 256, 0, stream>>>(ei, edge_e, offs, cursor,
                                                    pairs, nE, n);
    k_acc<<<(n + 3) / 4, 256, 0, stream>>>(pairs, offs, h, out, n);
}

// Round 3
// 328.551 us; speedup vs baseline: 1.5445x; 1.1349x over previous
//
#include <hip/hip_runtime.h>

#define IN_F 256
#define OUT_F 128
#define ALPHA 0.2f
#define EPS 9e-15f
#define NBUCK_MAX 512      // ceil(n/128) = 391 for n = 50000
#define CHUNK 4096

// ---------------- K1: h = input @ W, fused hs/hd epilogue ----------------
__global__ __launch_bounds__(256) void k_gemm(const float* __restrict__ input,
                                              const float* __restrict__ W,
                                              const float* __restrict__ a,
                                              float* __restrict__ h,
                                              float* __restrict__ hs,
                                              float* __restrict__ hd, int n) {
    __shared__ float Wt[64][128];
    __shared__ float It[64][128];
    const int t = threadIdx.x;
    const int row0 = blockIdx.x * 128;
    const int tx = t & 15;
    const int ty = t >> 4;

    float acc[8][8];
#pragma unroll
    for (int r = 0; r < 8; ++r)
#pragma unroll
        for (int c = 0; c < 8; ++c) acc[r][c] = 0.f;

    for (int k0 = 0; k0 < IN_F; k0 += 64) {
#pragma unroll
        for (int i = 0; i < 8; ++i) {
            int fidx = i * 256 + t;
            int wr = fidx >> 5, wc4 = fidx & 31;
            float4 v = *(const float4*)&W[(k0 + wr) * OUT_F + wc4 * 4];
            *(float4*)&Wt[wr][wc4 * 4] = v;
        }
#pragma unroll
        for (int i = 0; i < 8; ++i) {
            int fidx = i * 256 + t;
            int rr = fidx >> 4, c4 = fidx & 15;
            int grow = row0 + rr;
            float4 v = make_float4(0.f, 0.f, 0.f, 0.f);
            if (grow < n) v = *(const float4*)&input[grow * IN_F + k0 + c4 * 4];
            It[c4 * 4 + 0][rr] = v.x;
            It[c4 * 4 + 1][rr] = v.y;
            It[c4 * 4 + 2][rr] = v.z;
            It[c4 * 4 + 3][rr] = v.w;
        }
        __syncthreads();
#pragma unroll 8
        for (int kk = 0; kk < 64; ++kk) {
            float4 w0 = *(float4*)&Wt[kk][tx * 8];
            float4 w1 = *(float4*)&Wt[kk][tx * 8 + 4];
            float4 i0 = *(float4*)&It[kk][ty * 8];
            float4 i1 = *(float4*)&It[kk][ty * 8 + 4];
            float wv[8] = {w0.x, w0.y, w0.z, w0.w, w1.x, w1.y, w1.z, w1.w};
            float iv[8] = {i0.x, i0.y, i0.z, i0.w, i1.x, i1.y, i1.z, i1.w};
#pragma unroll
            for (int r = 0; r < 8; ++r)
#pragma unroll
                for (int c = 0; c < 8; ++c)
                    acc[r][c] = fmaf(iv[r], wv[c], acc[r][c]);
        }
        __syncthreads();
    }

    float as[8], ad[8];
#pragma unroll
    for (int c = 0; c < 8; ++c) {
        as[c] = a[tx * 8 + c];
        ad[c] = a[OUT_F + tx * 8 + c];
    }

#pragma unroll
    for (int r = 0; r < 8; ++r) {
        int grow = row0 + ty * 8 + r;
        float ps = 0.f, pd = 0.f;
#pragma unroll
        for (int c = 0; c < 8; ++c) {
            ps = fmaf(acc[r][c], as[c], ps);
            pd = fmaf(acc[r][c], ad[c], pd);
        }
#pragma unroll
        for (int o = 8; o; o >>= 1) {
            ps += __shfl_xor(ps, o);
            pd += __shfl_xor(pd, o);
        }
        if (grow < n) {
            float4 o0 = make_float4(acc[r][0], acc[r][1], acc[r][2], acc[r][3]);
            float4 o1 = make_float4(acc[r][4], acc[r][5], acc[r][6], acc[r][7]);
            *(float4*)&h[grow * OUT_F + tx * 8] = o0;
            *(float4*)&h[grow * OUT_F + tx * 8 + 4] = o1;
            if (tx == 0) { hs[grow] = ps; hd[grow] = pd; }
        }
    }
}

// ---------------- K2: node histogram + bucket histogram ----------------
__global__ __launch_bounds__(256) void k_hist(const int* __restrict__ ei,
                                              int* __restrict__ cnt,
                                              int* __restrict__ bcnt,
                                              int nE, int n) {
    __shared__ int bh[NBUCK_MAX];
    for (int i = threadIdx.x; i < NBUCK_MAX; i += 256) bh[i] = 0;
    __syncthreads();
    int stride = gridDim.x * 256;
    for (int e = blockIdx.x * 256 + threadIdx.x; e < nE; e += stride) {
        int s = ei[e];
        s = min(max(s, 0), n - 1);
        atomicAdd(&cnt[s], 1);
        atomicAdd(&bh[s >> 7], 1);
    }
    __syncthreads();
    int nbuck = (n + 127) >> 7;
    for (int i = threadIdx.x; i < nbuck; i += 256)
        if (bh[i]) atomicAdd(&bcnt[i], bh[i]);
}

// ---------------- node-count scan (3 kernels) ----------------
__global__ __launch_bounds__(256) void k_scan1(const int* __restrict__ cnt,
                                               int* __restrict__ offs,
                                               int* __restrict__ bsum, int n) {
    __shared__ int sA[512], sB[512];
    int t = threadIdx.x;
    int base = blockIdx.x * 512;
    sA[t] = (base + t < n) ? cnt[base + t] : 0;
    sA[t + 256] = (base + 256 + t < n) ? cnt[base + 256 + t] : 0;
    __syncthreads();
    int* src = sA;
    int* dst = sB;
    for (int ofs = 1; ofs < 512; ofs <<= 1) {
        dst[t] = src[t] + (t >= ofs ? src[t - ofs] : 0);
        int i1 = t + 256;
        dst[i1] = src[i1] + (i1 >= ofs ? src[i1 - ofs] : 0);
        __syncthreads();
        int* tmp = src; src = dst; dst = tmp;
    }
    if (base + t < n) offs[base + t] = t ? src[t - 1] : 0;
    if (base + 256 + t < n) offs[base + 256 + t] = src[t + 255];
    if (t == 0) bsum[blockIdx.x] = src[511];
}

__global__ __launch_bounds__(256) void k_scan2(const int* __restrict__ bsum,
                                               int* __restrict__ boffs,
                                               int nb, int* __restrict__ offs,
                                               int n, int nE) {
    __shared__ int s[256];
    int t = threadIdx.x;
    s[t] = (t < nb) ? bsum[t] : 0;
    __syncthreads();
    for (int ofs = 1; ofs < 256; ofs <<= 1) {
        int v = s[t];
        int u = (t >= ofs) ? s[t - ofs] : 0;
        __syncthreads();
        s[t] = v + u;
        __syncthreads();
    }
    if (t < nb) boffs[t] = t ? s[t - 1] : 0;
    if (t == 0) offs[n] = nE;
}

__global__ __launch_bounds__(256) void k_scan3(int* __restrict__ offs,
                                               const int* __restrict__ boffs, int n) {
    int i = blockIdx.x * 256 + threadIdx.x;
    if (i < n) offs[i] += boffs[i >> 9];
}

// ---------------- bucket scan: bcnt -> boffB (exclusive), init bcursor ----------------
__global__ __launch_bounds__(256) void k_scanB(const int* __restrict__ bcnt,
                                               int* __restrict__ boffB,
                                               int* __restrict__ bcursor,
                                               int nbuck) {
    __shared__ int sA[NBUCK_MAX], sB[NBUCK_MAX];
    int t = threadIdx.x;
    for (int i = t; i < NBUCK_MAX; i += 256) sA[i] = (i < nbuck) ? bcnt[i] : 0;
    __syncthreads();
    int *src = sA, *dst = sB;
    for (int ofs = 1; ofs < NBUCK_MAX; ofs <<= 1) {
        for (int i = t; i < NBUCK_MAX; i += 256)
            dst[i] = src[i] + (i >= ofs ? src[i - ofs] : 0);
        __syncthreads();
        int* tmp = src; src = dst; dst = tmp;
    }
    for (int i = t; i < nbuck; i += 256) {
        int ex = i ? src[i - 1] : 0;
        boffB[i] = ex;
        bcursor[i] = ex;
    }
}

// ---------------- K3: per-edge score -> edge_e ----------------
__global__ __launch_bounds__(256) void k_edge(const int* __restrict__ ei,
                                              const float* __restrict__ ew,
                                              const float* __restrict__ er,
                                              const float* __restrict__ hs,
                                              const float* __restrict__ hd,
                                              const float* __restrict__ Wr,
                                              const float* __restrict__ a,
                                              float* __restrict__ edge_e,
                                              int nE, int n) {
    __shared__ float war[8];
    {
        int t = threadIdx.x;
        int rr = t >> 5;
        int l5 = t & 31;
        float p = 0.f;
#pragma unroll
        for (int k = 0; k < 4; ++k)
            p = fmaf(Wr[rr * OUT_F + l5 * 4 + k], a[2 * OUT_F + l5 * 4 + k], p);
#pragma unroll
        for (int o = 16; o; o >>= 1) p += __shfl_xor(p, o, 32);
        if (l5 == 0) war[rr] = p;
    }
    __syncthreads();

    int e = blockIdx.x * 256 + threadIdx.x;
    if (e >= nE) return;
    int s = ei[e], d = ei[nE + e];
    s = min(max(s, 0), n - 1);
    d = min(max(d, 0), n - 1);
    float4 r0 = *(const float4*)&er[e * 8];
    float4 r1 = *(const float4*)&er[e * 8 + 4];
    float sc = hs[s] + hd[d]
             + r0.x * war[0] + r0.y * war[1] + r0.z * war[2] + r0.w * war[3]
             + r1.x * war[4] + r1.y * war[5] + r1.z * war[6] + r1.w * war[7]
             + a[3 * OUT_F] * ew[e];
    float lr = sc > 0.f ? sc : ALPHA * sc;
    edge_e[e] = expf(-lr);
}

// ---------------- K4: binned coarse scatter ----------------
// Each block: CHUNK edges -> per-bucket local ranks in LDS, one range
// reservation atomic per (block,bucket), contiguous record writes.
// Record: x = dst | (s&127)<<16 ; y = bits(edge_e)
__global__ __launch_bounds__(256) void k_bin(const int* __restrict__ ei,
                                             const float* __restrict__ edge_e,
                                             int* __restrict__ bcursor,
                                             int2* __restrict__ binned,
                                             int nE, int n) {
    __shared__ int bcl[NBUCK_MAX];
    __shared__ int gbase[NBUCK_MAX];
    __shared__ unsigned int tmp[CHUNK];
    const int t = threadIdx.x;
    const int base = blockIdx.x * CHUNK;
    for (int i = t; i < NBUCK_MAX; i += 256) bcl[i] = 0;
    __syncthreads();
#pragma unroll
    for (int r = 0; r < CHUNK / 256; ++r) {
        int i = r * 256 + t;
        int e = base + i;
        if (e < nE) {
            int s = ei[e];
            s = min(max(s, 0), n - 1);
            int b = s >> 7;
            int lr = atomicAdd(&bcl[b], 1);
            tmp[i] = ((unsigned)b << 12) | (unsigned)lr;   // lr < 4096
        }
    }
    __syncthreads();
    for (int i = t; i < NBUCK_MAX; i += 256) {
        int c = bcl[i];
        gbase[i] = c ? atomicAdd(&bcursor[i], c) : 0;
    }
    __syncthreads();
#pragma unroll
    for (int r = 0; r < CHUNK / 256; ++r) {
        int i = r * 256 + t;
        int e = base + i;
        if (e < nE) {
            unsigned u = tmp[i];
            int b = u >> 12;
            int lr = u & 4095;
            int s = ei[e];
            s = min(max(s, 0), n - 1);
            int d = ei[nE + e];
            d = min(max(d, 0), n - 1);
            int2 pr;
            pr.x = (d & 0xFFFF) | ((s & 127) << 16);
            pr.y = __float_as_int(edge_e[e]);
            binned[gbase[b] + lr] = pr;
        }
    }
}

// ---------------- K5: within-bucket scatter to final CSR order ----------------
__global__ __launch_bounds__(256) void k_sub(const int2* __restrict__ binned,
                                             const int* __restrict__ bcnt,
                                             const int* __restrict__ boffB,
                                             const int* __restrict__ offs,
                                             int2* __restrict__ pairs, int n) {
    __shared__ int cur[128];
    __shared__ int loffs[128];
    int b = blockIdx.x;
    int t = threadIdx.x;
    int node0 = b << 7;
    if (t < 128) {
        cur[t] = 0;
        loffs[t] = (node0 + t < n) ? offs[node0 + t] : 0;
    }
    __syncthreads();
    int beg = boffB[b], c = bcnt[b];
    for (int i = t; i < c; i += 256) {
        int2 pr = binned[beg + i];
        int sl = (pr.x >> 16) & 127;
        int pos = loffs[sl] + atomicAdd(&cur[sl], 1);
        int2 o;
        o.x = pr.x & 0xFFFF;
        o.y = pr.y;
        pairs[pos] = o;
    }
}

// ---------------- K6: per-node accumulation + finalize (elu) ----------------
__global__ __launch_bounds__(256) void k_acc(const int2* __restrict__ pairs,
                                             const int* __restrict__ offs,
                                             const float* __restrict__ h,
                                             float* __restrict__ out, int n) {
    int wid = threadIdx.x >> 6, lane = threadIdx.x & 63;
    int node = blockIdx.x * 4 + wid;
    if (node >= n) return;
    int beg = offs[node], end = offs[node + 1];
    float ax = 0.f, ay = 0.f, rowsum = 0.f;
    int idx = beg;
    for (; idx + 8 <= end; idx += 8) {
        int2 p[8];
        float2 hv[8];
#pragma unroll
        for (int j = 0; j < 8; ++j) p[j] = pairs[idx + j];
#pragma unroll
        for (int j = 0; j < 8; ++j)
            hv[j] = *(const float2*)&h[(size_t)p[j].x * OUT_F + lane * 2];
#pragma unroll
        for (int j = 0; j < 8; ++j) {
            float ee = __int_as_float(p[j].y);
            ax = fmaf(ee, hv[j].x, ax);
            ay = fmaf(ee, hv[j].y, ay);
            rowsum += ee;
        }
    }
    for (; idx < end; ++idx) {
        int2 p = pairs[idx];
        float ee = __int_as_float(p.y);
        float2 hv = *(const float2*)&h[(size_t)p.x * OUT_F + lane * 2];
        ax = fmaf(ee, hv.x, ax);
        ay = fmaf(ee, hv.y, ay);
        rowsum += ee;
    }
    float inv = 1.f / (rowsum + EPS);
    float x = ax * inv, y = ay * inv;
    x = x > 0.f ? x : (expf(x) - 1.f);
    y = y > 0.f ? y : (expf(y) - 1.f);
    float2 o = make_float2(x, y);
    *(float2*)&out[node * OUT_F + lane * 2] = o;
}

static inline size_t align_up(size_t v, size_t al) { return (v + al - 1) & ~(al - 1); }

extern "C" void kernel_launch(void* const* d_in, const int* in_sizes, int n_in,
                              void* d_out, int out_size, void* d_ws, size_t ws_size,
                              hipStream_t stream) {
    const float* input = (const float*)d_in[0];
    const int*   ei    = (const int*)d_in[1];
    const float* ew    = (const float*)d_in[2];
    const float* er    = (const float*)d_in[3];
    const float* W     = (const float*)d_in[4];
    const float* Wr    = (const float*)d_in[5];
    const float* a     = (const float*)d_in[6];
    float* out = (float*)d_out;

    const int n  = in_sizes[0] / IN_F;   // 50000
    const int nE = in_sizes[2];          // 1600000
    const int nbuck = (n + 127) >> 7;    // 391

    char* p = (char*)d_ws;
    size_t o = 0;
    float* h       = (float*)(p + o); o = align_up(o + (size_t)n * OUT_F * 4, 256);
    float* hs      = (float*)(p + o); o = align_up(o + (size_t)n * 4, 256);
    float* hd      = (float*)(p + o); o = align_up(o + (size_t)n * 4, 256);
    float* edge_e  = (float*)(p + o); o = align_up(o + (size_t)nE * 4, 256);
    int*   cnt     = (int*)(p + o);   o = align_up(o + (size_t)n * 4, 256);
    int*   offs    = (int*)(p + o);   o = align_up(o + (size_t)(n + 1) * 4, 256);
    int2*  pairs   = (int2*)(p + o);  o = align_up(o + (size_t)nE * 8, 256);
    int2*  binned  = (int2*)(p + o);  o = align_up(o + (size_t)nE * 8, 256);
    int*   bcnt    = (int*)(p + o);   o = align_up(o + NBUCK_MAX * 4, 256);
    int*   boffB   = (int*)(p + o);   o = align_up(o + NBUCK_MAX * 4, 256);
    int*   bcursor = (int*)(p + o);   o = align_up(o + NBUCK_MAX * 4, 256);
    int*   bsum    = (int*)(p + o);   o = align_up(o + 4096, 256);
    int*   boffs   = (int*)(p + o);   o = align_up(o + 4096, 256);
    (void)ws_size; (void)n_in; (void)out_size;

    hipMemsetAsync(cnt, 0, (size_t)n * 4, stream);
    hipMemsetAsync(bcnt, 0, NBUCK_MAX * 4, stream);

    k_gemm<<<(n + 127) / 128, 256, 0, stream>>>(input, W, a, h, hs, hd, n);
    k_hist<<<1024, 256, 0, stream>>>(ei, cnt, bcnt, nE, n);
    int nb = (n + 511) / 512;
    k_scan1<<<nb, 256, 0, stream>>>(cnt, offs, bsum, n);
    k_scan2<<<1, 256, 0, stream>>>(bsum, boffs, nb, offs, n, nE);
    k_scan3<<<(n + 255) / 256, 256, 0, stream>>>(offs, boffs, n);
    k_scanB<<<1, 256, 0, stream>>>(bcnt, boffB, bcursor, nbuck);
    k_edge<<<(nE + 255) / 256, 256, 0, stream>>>(ei, ew, er, hs, hd, Wr, a,
                                                 edge_e, nE, n);
    int nchunk = (nE + CHUNK - 1) / CHUNK;
    k_bin<<<nchunk, 256, 0, stream>>>(ei, edge_e, bcursor, binned, nE, n);
    k_sub<<<nbuck, 256, 0, stream>>>(binned, bcnt, boffB, offs, pairs, n);
    k_acc<<<(n + 3) / 4, 256, 0, stream>>>(pairs, offs, h, out, n);
}

// Round 4
// 269.082 us; speedup vs baseline: 1.8859x; 1.2210x over previous
//
#include <hip/hip_runtime.h>

#define IN_F 256
#define OUT_F 128
#define ALPHA 0.2f
#define EPS 9e-15f
#define NBUCK_MAX 512      // ceil(n/128) = 391 for n = 50000
#define CHUNK 4096

__device__ __forceinline__ unsigned bf16rnd(float f) {
    unsigned b = __float_as_uint(f);
    return b + 0x7FFFu + ((b >> 16) & 1u);   // caller takes >>16 or &0xFFFF0000
}

// ---------------- K1: h = input @ W, fused hs/hd epilogue, bf16-packed h ----------------
__global__ __launch_bounds__(256) void k_gemm(const float* __restrict__ input,
                                              const float* __restrict__ W,
                                              const float* __restrict__ a,
                                              unsigned* __restrict__ hb,   // n x 64 uints (2 bf16 each)
                                              float* __restrict__ hs,
                                              float* __restrict__ hd, int n) {
    __shared__ float Wt[64][128];
    __shared__ float It[64][128];
    const int t = threadIdx.x;
    const int row0 = blockIdx.x * 128;
    const int tx = t & 15;
    const int ty = t >> 4;

    float acc[8][8];
#pragma unroll
    for (int r = 0; r < 8; ++r)
#pragma unroll
        for (int c = 0; c < 8; ++c) acc[r][c] = 0.f;

    for (int k0 = 0; k0 < IN_F; k0 += 64) {
#pragma unroll
        for (int i = 0; i < 8; ++i) {
            int fidx = i * 256 + t;
            int wr = fidx >> 5, wc4 = fidx & 31;
            float4 v = *(const float4*)&W[(k0 + wr) * OUT_F + wc4 * 4];
            *(float4*)&Wt[wr][wc4 * 4] = v;
        }
#pragma unroll
        for (int i = 0; i < 8; ++i) {
            int fidx = i * 256 + t;
            int rr = fidx >> 4, c4 = fidx & 15;
            int grow = row0 + rr;
            float4 v = make_float4(0.f, 0.f, 0.f, 0.f);
            if (grow < n) v = *(const float4*)&input[grow * IN_F + k0 + c4 * 4];
            It[c4 * 4 + 0][rr] = v.x;
            It[c4 * 4 + 1][rr] = v.y;
            It[c4 * 4 + 2][rr] = v.z;
            It[c4 * 4 + 3][rr] = v.w;
        }
        __syncthreads();
#pragma unroll 8
        for (int kk = 0; kk < 64; ++kk) {
            float4 w0 = *(float4*)&Wt[kk][tx * 8];
            float4 w1 = *(float4*)&Wt[kk][tx * 8 + 4];
            float4 i0 = *(float4*)&It[kk][ty * 8];
            float4 i1 = *(float4*)&It[kk][ty * 8 + 4];
            float wv[8] = {w0.x, w0.y, w0.z, w0.w, w1.x, w1.y, w1.z, w1.w};
            float iv[8] = {i0.x, i0.y, i0.z, i0.w, i1.x, i1.y, i1.z, i1.w};
#pragma unroll
            for (int r = 0; r < 8; ++r)
#pragma unroll
                for (int c = 0; c < 8; ++c)
                    acc[r][c] = fmaf(iv[r], wv[c], acc[r][c]);
        }
        __syncthreads();
    }

    float as[8], ad[8];
#pragma unroll
    for (int c = 0; c < 8; ++c) {
        as[c] = a[tx * 8 + c];
        ad[c] = a[OUT_F + tx * 8 + c];
    }

#pragma unroll
    for (int r = 0; r < 8; ++r) {
        int grow = row0 + ty * 8 + r;
        float ps = 0.f, pd = 0.f;
#pragma unroll
        for (int c = 0; c < 8; ++c) {
            ps = fmaf(acc[r][c], as[c], ps);
            pd = fmaf(acc[r][c], ad[c], pd);
        }
#pragma unroll
        for (int o = 8; o; o >>= 1) {
            ps += __shfl_xor(ps, o);
            pd += __shfl_xor(pd, o);
        }
        if (grow < n) {
            uint4 pk;
            pk.x = (bf16rnd(acc[r][0]) >> 16) | (bf16rnd(acc[r][1]) & 0xFFFF0000u);
            pk.y = (bf16rnd(acc[r][2]) >> 16) | (bf16rnd(acc[r][3]) & 0xFFFF0000u);
            pk.z = (bf16rnd(acc[r][4]) >> 16) | (bf16rnd(acc[r][5]) & 0xFFFF0000u);
            pk.w = (bf16rnd(acc[r][6]) >> 16) | (bf16rnd(acc[r][7]) & 0xFFFF0000u);
            *(uint4*)&hb[(size_t)grow * 64 + tx * 4] = pk;
            if (tx == 0) { hs[grow] = ps; hd[grow] = pd; }
        }
    }
}

// ---------------- node-count scan (3 kernels) ----------------
__global__ __launch_bounds__(256) void k_scan1(const int* __restrict__ cnt,
                                               int* __restrict__ offs,
                                               int* __restrict__ bsum, int n) {
    __shared__ int sA[512], sB[512];
    int t = threadIdx.x;
    int base = blockIdx.x * 512;
    sA[t] = (base + t < n) ? cnt[base + t] : 0;
    sA[t + 256] = (base + 256 + t < n) ? cnt[base + 256 + t] : 0;
    __syncthreads();
    int* src = sA;
    int* dst = sB;
    for (int ofs = 1; ofs < 512; ofs <<= 1) {
        dst[t] = src[t] + (t >= ofs ? src[t - ofs] : 0);
        int i1 = t + 256;
        dst[i1] = src[i1] + (i1 >= ofs ? src[i1 - ofs] : 0);
        __syncthreads();
        int* tmp = src; src = dst; dst = tmp;
    }
    if (base + t < n) offs[base + t] = t ? src[t - 1] : 0;
    if (base + 256 + t < n) offs[base + 256 + t] = src[t + 255];
    if (t == 0) bsum[blockIdx.x] = src[511];
}

__global__ __launch_bounds__(256) void k_scan2(const int* __restrict__ bsum,
                                               int* __restrict__ boffs,
                                               int nb, int* __restrict__ offs,
                                               int n, int nE) {
    __shared__ int s[256];
    int t = threadIdx.x;
    s[t] = (t < nb) ? bsum[t] : 0;
    __syncthreads();
    for (int ofs = 1; ofs < 256; ofs <<= 1) {
        int v = s[t];
        int u = (t >= ofs) ? s[t - ofs] : 0;
        __syncthreads();
        s[t] = v + u;
        __syncthreads();
    }
    if (t < nb) boffs[t] = t ? s[t - 1] : 0;
    if (t == 0) offs[n] = nE;
}

__global__ __launch_bounds__(256) void k_scan3(int* __restrict__ offs,
                                               const int* __restrict__ boffs, int n) {
    int i = blockIdx.x * 256 + threadIdx.x;
    if (i < n) offs[i] += boffs[i >> 9];
}

// ---------------- bucket scan ----------------
__global__ __launch_bounds__(256) void k_scanB(const int* __restrict__ bcnt,
                                               int* __restrict__ boffB,
                                               int* __restrict__ bcursor,
                                               int nbuck) {
    __shared__ int sA[NBUCK_MAX], sB[NBUCK_MAX];
    int t = threadIdx.x;
    for (int i = t; i < NBUCK_MAX; i += 256) sA[i] = (i < nbuck) ? bcnt[i] : 0;
    __syncthreads();
    int *src = sA, *dst = sB;
    for (int ofs = 1; ofs < NBUCK_MAX; ofs <<= 1) {
        for (int i = t; i < NBUCK_MAX; i += 256)
            dst[i] = src[i] + (i >= ofs ? src[i - ofs] : 0);
        __syncthreads();
        int* tmp = src; src = dst; dst = tmp;
    }
    for (int i = t; i < nbuck; i += 256) {
        int ex = i ? src[i - 1] : 0;
        boffB[i] = ex;
        bcursor[i] = ex;
    }
}

// ---------------- K2: per-edge score -> edge_e, fused node+bucket histogram ----------------
__global__ __launch_bounds__(256) void k_edge(const int* __restrict__ ei,
                                              const float* __restrict__ ew,
                                              const float* __restrict__ er,
                                              const float* __restrict__ hs,
                                              const float* __restrict__ hd,
                                              const float* __restrict__ Wr,
                                              const float* __restrict__ a,
                                              float* __restrict__ edge_e,
                                              int* __restrict__ cnt,
                                              int* __restrict__ bcnt,
                                              int nE, int n) {
    __shared__ float war[8];
    __shared__ int bh[NBUCK_MAX];
    const int t = threadIdx.x;
    for (int i = t; i < NBUCK_MAX; i += 256) bh[i] = 0;
    {
        int rr = t >> 5;
        int l5 = t & 31;
        float p = 0.f;
#pragma unroll
        for (int k = 0; k < 4; ++k)
            p = fmaf(Wr[rr * OUT_F + l5 * 4 + k], a[2 * OUT_F + l5 * 4 + k], p);
#pragma unroll
        for (int o = 16; o; o >>= 1) p += __shfl_xor(p, o, 32);
        if (l5 == 0) war[rr] = p;
    }
    __syncthreads();

    float aw = a[3 * OUT_F];
    int stride = gridDim.x * 256;
    for (int e = blockIdx.x * 256 + t; e < nE; e += stride) {
        int s = ei[e], d = ei[nE + e];
        s = min(max(s, 0), n - 1);
        d = min(max(d, 0), n - 1);
        float4 r0 = *(const float4*)&er[(size_t)e * 8];
        float4 r1 = *(const float4*)&er[(size_t)e * 8 + 4];
        float sc = hs[s] + hd[d]
                 + r0.x * war[0] + r0.y * war[1] + r0.z * war[2] + r0.w * war[3]
                 + r1.x * war[4] + r1.y * war[5] + r1.z * war[6] + r1.w * war[7]
                 + aw * ew[e];
        float lr = sc > 0.f ? sc : ALPHA * sc;
        edge_e[e] = expf(-lr);
        atomicAdd(&cnt[s], 1);
        atomicAdd(&bh[s >> 7], 1);
    }
    __syncthreads();
    int nbuck = (n + 127) >> 7;
    for (int i = t; i < nbuck; i += 256)
        if (bh[i]) atomicAdd(&bcnt[i], bh[i]);
}

// ---------------- K4: binned coarse scatter ----------------
// tmp word: [0:12)=local rank, [12:21)=bucket, [21:28)=s&127
__global__ __launch_bounds__(256) void k_bin(const int* __restrict__ ei,
                                             const float* __restrict__ edge_e,
                                             int* __restrict__ bcursor,
                                             int2* __restrict__ binned,
                                             int nE, int n) {
    __shared__ int bcl[NBUCK_MAX];
    __shared__ int gbase[NBUCK_MAX];
    __shared__ unsigned int tmp[CHUNK];
    const int t = threadIdx.x;
    const int base = blockIdx.x * CHUNK;
    for (int i = t; i < NBUCK_MAX; i += 256) bcl[i] = 0;
    __syncthreads();
#pragma unroll
    for (int r = 0; r < CHUNK / 256; ++r) {
        int i = r * 256 + t;
        int e = base + i;
        if (e < nE) {
            int s = ei[e];
            s = min(max(s, 0), n - 1);
            int b = s >> 7;
            int lr = atomicAdd(&bcl[b], 1);
            tmp[i] = ((unsigned)b << 12) | (unsigned)lr | ((unsigned)(s & 127) << 21);
        }
    }
    __syncthreads();
    for (int i = t; i < NBUCK_MAX; i += 256) {
        int c = bcl[i];
        gbase[i] = c ? atomicAdd(&bcursor[i], c) : 0;
    }
    __syncthreads();
#pragma unroll
    for (int r = 0; r < CHUNK / 256; ++r) {
        int i = r * 256 + t;
        int e = base + i;
        if (e < nE) {
            unsigned u = tmp[i];
            int b = (u >> 12) & 0x1FF;
            int lr = u & 4095;
            int sl = (u >> 21) & 127;
            int d = ei[nE + e];
            d = min(max(d, 0), n - 1);
            int2 pr;
            pr.x = (d & 0xFFFF) | (sl << 16);
            pr.y = __float_as_int(edge_e[e]);
            binned[gbase[b] + lr] = pr;
        }
    }
}

// ---------------- K5: within-bucket scatter to final CSR order ----------------
__global__ __launch_bounds__(256) void k_sub(const int2* __restrict__ binned,
                                             const int* __restrict__ bcnt,
                                             const int* __restrict__ boffB,
                                             const int* __restrict__ offs,
                                             int2* __restrict__ pairs, int n) {
    __shared__ int cur[128];
    __shared__ int loffs[128];
    int b = blockIdx.x;
    int t = threadIdx.x;
    int node0 = b << 7;
    if (t < 128) {
        cur[t] = 0;
        loffs[t] = (node0 + t < n) ? offs[node0 + t] : 0;
    }
    __syncthreads();
    int beg = boffB[b], c = bcnt[b];
    for (int i = t; i < c; i += 256) {
        int2 pr = binned[beg + i];
        int sl = (pr.x >> 16) & 127;
        int pos = loffs[sl] + atomicAdd(&cur[sl], 1);
        int2 o;
        o.x = pr.x & 0xFFFF;
        o.y = pr.y;
        pairs[pos] = o;
    }
}

// ---------------- K6: per-node accumulation + finalize (elu), bf16 h gather ----------------
__global__ __launch_bounds__(256) void k_acc(const int2* __restrict__ pairs,
                                             const int* __restrict__ offs,
                                             const unsigned* __restrict__ hb,
                                             float* __restrict__ out, int n) {
    int wid = threadIdx.x >> 6, lane = threadIdx.x & 63;
    int node = blockIdx.x * 4 + wid;
    if (node >= n) return;
    int beg = offs[node], end = offs[node + 1];
    float ax = 0.f, ay = 0.f, rowsum = 0.f;
    int idx = beg;
    for (; idx + 8 <= end; idx += 8) {
        int2 p[8];
        unsigned u[8];
#pragma unroll
        for (int j = 0; j < 8; ++j) p[j] = pairs[idx + j];
#pragma unroll
        for (int j = 0; j < 8; ++j)
            u[j] = hb[(size_t)p[j].x * 64 + lane];
#pragma unroll
        for (int j = 0; j < 8; ++j) {
            float ee = __int_as_float(p[j].y);
            float hx = __uint_as_float(u[j] << 16);
            float hy = __uint_as_float(u[j] & 0xFFFF0000u);
            ax = fmaf(ee, hx, ax);
            ay = fmaf(ee, hy, ay);
            rowsum += ee;
        }
    }
    for (; idx < end; ++idx) {
        int2 p = pairs[idx];
        float ee = __int_as_float(p.y);
        unsigned u = hb[(size_t)p.x * 64 + lane];
        float hx = __uint_as_float(u << 16);
        float hy = __uint_as_float(u & 0xFFFF0000u);
        ax = fmaf(ee, hx, ax);
        ay = fmaf(ee, hy, ay);
        rowsum += ee;
    }
    float inv = 1.f / (rowsum + EPS);
    float x = ax * inv, y = ay * inv;
    x = x > 0.f ? x : (expf(x) - 1.f);
    y = y > 0.f ? y : (expf(y) - 1.f);
    float2 o = make_float2(x, y);
    *(float2*)&out[node * OUT_F + lane * 2] = o;
}

static inline size_t align_up(size_t v, size_t al) { return (v + al - 1) & ~(al - 1); }

extern "C" void kernel_launch(void* const* d_in, const int* in_sizes, int n_in,
                              void* d_out, int out_size, void* d_ws, size_t ws_size,
                              hipStream_t stream) {
    const float* input = (const float*)d_in[0];
    const int*   ei    = (const int*)d_in[1];
    const float* ew    = (const float*)d_in[2];
    const float* er    = (const float*)d_in[3];
    const float* W     = (const float*)d_in[4];
    const float* Wr    = (const float*)d_in[5];
    const float* a     = (const float*)d_in[6];
    float* out = (float*)d_out;

    const int n  = in_sizes[0] / IN_F;   // 50000
    const int nE = in_sizes[2];          // 1600000
    const int nbuck = (n + 127) >> 7;    // 391

    char* p = (char*)d_ws;
    size_t o = 0;
    unsigned* hb   = (unsigned*)(p + o); o = align_up(o + (size_t)n * 64 * 4, 256);
    float* hs      = (float*)(p + o); o = align_up(o + (size_t)n * 4, 256);
    float* hd      = (float*)(p + o); o = align_up(o + (size_t)n * 4, 256);
    float* edge_e  = (float*)(p + o); o = align_up(o + (size_t)nE * 4, 256);
    int*   cnt     = (int*)(p + o);   o = align_up(o + (size_t)n * 4, 256);
    int*   offs    = (int*)(p + o);   o = align_up(o + (size_t)(n + 1) * 4, 256);
    int2*  pairs   = (int2*)(p + o);  o = align_up(o + (size_t)nE * 8, 256);
    int2*  binned  = (int2*)(p + o);  o = align_up(o + (size_t)nE * 8, 256);
    int*   bcnt    = (int*)(p + o);   o = align_up(o + NBUCK_MAX * 4, 256);
    int*   boffB   = (int*)(p + o);   o = align_up(o + NBUCK_MAX * 4, 256);
    int*   bcursor = (int*)(p + o);   o = align_up(o + NBUCK_MAX * 4, 256);
    int*   bsum    = (int*)(p + o);   o = align_up(o + 4096, 256);
    int*   boffs   = (int*)(p + o);   o = align_up(o + 4096, 256);
    (void)ws_size; (void)n_in; (void)out_size;

    hipMemsetAsync(cnt, 0, (size_t)n * 4, stream);
    hipMemsetAsync(bcnt, 0, NBUCK_MAX * 4, stream);

    k_gemm<<<(n + 127) / 128, 256, 0, stream>>>(input, W, a, hb, hs, hd, n);
    k_edge<<<1024, 256, 0, stream>>>(ei, ew, er, hs, hd, Wr, a, edge_e,
                                     cnt, bcnt, nE, n);
    int nb = (n + 511) / 512;
    k_scan1<<<nb, 256, 0, stream>>>(cnt, offs, bsum, n);
    k_scan2<<<1, 256, 0, stream>>>(bsum, boffs, nb, offs, n, nE);
    k_scan3<<<(n + 255) / 256, 256, 0, stream>>>(offs, boffs, n);
    k_scanB<<<1, 256, 0, stream>>>(bcnt, boffB, bcursor, nbuck);
    int nchunk = (nE + CHUNK - 1) / CHUNK;
    k_bin<<<nchunk, 256, 0, stream>>>(ei, edge_e, bcursor, binned, nE, n);
    k_sub<<<nbuck, 256, 0, stream>>>(binned, bcnt, boffB, offs, pairs, n);
    k_acc<<<(n + 3) / 4, 256, 0, stream>>>(pairs, offs, hb, out, n);
}

// Round 5
// 210.413 us; speedup vs baseline: 2.4117x; 1.2788x over previous
//
#include <hip/hip_runtime.h>

#define IN_F 256
#define OUT_F 128
#define ALPHA 0.2f
#define EPS 9e-15f
#define NBUCK_MAX 512      // ceil(n/128) = 391 for n = 50000
#define CHUNK 4096

__device__ __forceinline__ unsigned bf16rnd(float f) {
    unsigned b = __float_as_uint(f);
    return b + 0x7FFFu + ((b >> 16) & 1u);   // caller takes >>16 or &0xFFFF0000
}

// ---------------- K1: h = input @ W, fused hs/hd epilogue, bf16-packed h ----------------
__global__ __launch_bounds__(256) void k_gemm(const float* __restrict__ input,
                                              const float* __restrict__ W,
                                              const float* __restrict__ a,
                                              unsigned* __restrict__ hb,   // n x 64 uints (2 bf16 each)
                                              float* __restrict__ hs,
                                              float* __restrict__ hd, int n) {
    __shared__ float Wt[64][128];
    __shared__ float It[64][128];
    const int t = threadIdx.x;
    const int row0 = blockIdx.x * 128;
    const int tx = t & 15;
    const int ty = t >> 4;

    float acc[8][8];
#pragma unroll
    for (int r = 0; r < 8; ++r)
#pragma unroll
        for (int c = 0; c < 8; ++c) acc[r][c] = 0.f;

    for (int k0 = 0; k0 < IN_F; k0 += 64) {
#pragma unroll
        for (int i = 0; i < 8; ++i) {
            int fidx = i * 256 + t;
            int wr = fidx >> 5, wc4 = fidx & 31;
            float4 v = *(const float4*)&W[(k0 + wr) * OUT_F + wc4 * 4];
            *(float4*)&Wt[wr][wc4 * 4] = v;
        }
#pragma unroll
        for (int i = 0; i < 8; ++i) {
            int fidx = i * 256 + t;
            int rr = fidx >> 4, c4 = fidx & 15;
            int grow = row0 + rr;
            float4 v = make_float4(0.f, 0.f, 0.f, 0.f);
            if (grow < n) v = *(const float4*)&input[grow * IN_F + k0 + c4 * 4];
            It[c4 * 4 + 0][rr] = v.x;
            It[c4 * 4 + 1][rr] = v.y;
            It[c4 * 4 + 2][rr] = v.z;
            It[c4 * 4 + 3][rr] = v.w;
        }
        __syncthreads();
#pragma unroll 8
        for (int kk = 0; kk < 64; ++kk) {
            float4 w0 = *(float4*)&Wt[kk][tx * 8];
            float4 w1 = *(float4*)&Wt[kk][tx * 8 + 4];
            float4 i0 = *(float4*)&It[kk][ty * 8];
            float4 i1 = *(float4*)&It[kk][ty * 8 + 4];
            float wv[8] = {w0.x, w0.y, w0.z, w0.w, w1.x, w1.y, w1.z, w1.w};
            float iv[8] = {i0.x, i0.y, i0.z, i0.w, i1.x, i1.y, i1.z, i1.w};
#pragma unroll
            for (int r = 0; r < 8; ++r)
#pragma unroll
                for (int c = 0; c < 8; ++c)
                    acc[r][c] = fmaf(iv[r], wv[c], acc[r][c]);
        }
        __syncthreads();
    }

    float as[8], ad[8];
#pragma unroll
    for (int c = 0; c < 8; ++c) {
        as[c] = a[tx * 8 + c];
        ad[c] = a[OUT_F + tx * 8 + c];
    }

#pragma unroll
    for (int r = 0; r < 8; ++r) {
        int grow = row0 + ty * 8 + r;
        float ps = 0.f, pd = 0.f;
#pragma unroll
        for (int c = 0; c < 8; ++c) {
            ps = fmaf(acc[r][c], as[c], ps);
            pd = fmaf(acc[r][c], ad[c], pd);
        }
#pragma unroll
        for (int o = 8; o; o >>= 1) {
            ps += __shfl_xor(ps, o);
            pd += __shfl_xor(pd, o);
        }
        if (grow < n) {
            uint4 pk;
            pk.x = (bf16rnd(acc[r][0]) >> 16) | (bf16rnd(acc[r][1]) & 0xFFFF0000u);
            pk.y = (bf16rnd(acc[r][2]) >> 16) | (bf16rnd(acc[r][3]) & 0xFFFF0000u);
            pk.z = (bf16rnd(acc[r][4]) >> 16) | (bf16rnd(acc[r][5]) & 0xFFFF0000u);
            pk.w = (bf16rnd(acc[r][6]) >> 16) | (bf16rnd(acc[r][7]) & 0xFFFF0000u);
            *(uint4*)&hb[(size_t)grow * 64 + tx * 4] = pk;
            if (tx == 0) { hs[grow] = ps; hd[grow] = pd; }
        }
    }
}

// ---------------- bucket scan: bcnt -> boffB (exclusive), init bcursor ----------------
__global__ __launch_bounds__(256) void k_scanB(const int* __restrict__ bcnt,
                                               int* __restrict__ boffB,
                                               int* __restrict__ bcursor,
                                               int* __restrict__ offs,
                                               int nbuck, int n, int nE) {
    __shared__ int sA[NBUCK_MAX], sB[NBUCK_MAX];
    int t = threadIdx.x;
    for (int i = t; i < NBUCK_MAX; i += 256) sA[i] = (i < nbuck) ? bcnt[i] : 0;
    __syncthreads();
    int *src = sA, *dst = sB;
    for (int ofs = 1; ofs < NBUCK_MAX; ofs <<= 1) {
        for (int i = t; i < NBUCK_MAX; i += 256)
            dst[i] = src[i] + (i >= ofs ? src[i - ofs] : 0);
        __syncthreads();
        int* tmp = src; src = dst; dst = tmp;
    }
    for (int i = t; i < nbuck; i += 256) {
        int ex = i ? src[i - 1] : 0;
        boffB[i] = ex;
        bcursor[i] = ex;
    }
    if (t == 0) offs[n] = nE;
}

// ---------------- K2: per-edge score -> edge_e, fused bucket histogram ----------------
__global__ __launch_bounds__(256) void k_edge(const int* __restrict__ ei,
                                              const float* __restrict__ ew,
                                              const float* __restrict__ er,
                                              const float* __restrict__ hs,
                                              const float* __restrict__ hd,
                                              const float* __restrict__ Wr,
                                              const float* __restrict__ a,
                                              float* __restrict__ edge_e,
                                              int* __restrict__ bcnt,
                                              int nE, int n) {
    __shared__ float war[8];
    __shared__ int bh[NBUCK_MAX];
    const int t = threadIdx.x;
    for (int i = t; i < NBUCK_MAX; i += 256) bh[i] = 0;
    {
        int rr = t >> 5;
        int l5 = t & 31;
        float p = 0.f;
#pragma unroll
        for (int k = 0; k < 4; ++k)
            p = fmaf(Wr[rr * OUT_F + l5 * 4 + k], a[2 * OUT_F + l5 * 4 + k], p);
#pragma unroll
        for (int o = 16; o; o >>= 1) p += __shfl_xor(p, o, 32);
        if (l5 == 0) war[rr] = p;
    }
    __syncthreads();

    float aw = a[3 * OUT_F];
    int stride = gridDim.x * 256;
    for (int e = blockIdx.x * 256 + t; e < nE; e += stride) {
        int s = ei[e], d = ei[nE + e];
        s = min(max(s, 0), n - 1);
        d = min(max(d, 0), n - 1);
        float4 r0 = *(const float4*)&er[(size_t)e * 8];
        float4 r1 = *(const float4*)&er[(size_t)e * 8 + 4];
        float sc = hs[s] + hd[d]
                 + r0.x * war[0] + r0.y * war[1] + r0.z * war[2] + r0.w * war[3]
                 + r1.x * war[4] + r1.y * war[5] + r1.z * war[6] + r1.w * war[7]
                 + aw * ew[e];
        float lr = sc > 0.f ? sc : ALPHA * sc;
        edge_e[e] = expf(-lr);
        atomicAdd(&bh[s >> 7], 1);
    }
    __syncthreads();
    int nbuck = (n + 127) >> 7;
    for (int i = t; i < nbuck; i += 256)
        if (bh[i]) atomicAdd(&bcnt[i], bh[i]);
}

// ---------------- K4: binned coarse scatter ----------------
// tmp word: [0:12)=local rank, [12:21)=bucket, [21:28)=s&127
__global__ __launch_bounds__(256) void k_bin(const int* __restrict__ ei,
                                             const float* __restrict__ edge_e,
                                             int* __restrict__ bcursor,
                                             int2* __restrict__ binned,
                                             int nE, int n) {
    __shared__ int bcl[NBUCK_MAX];
    __shared__ int gbase[NBUCK_MAX];
    __shared__ unsigned int tmp[CHUNK];
    const int t = threadIdx.x;
    const int base = blockIdx.x * CHUNK;
    for (int i = t; i < NBUCK_MAX; i += 256) bcl[i] = 0;
    __syncthreads();
#pragma unroll
    for (int r = 0; r < CHUNK / 256; ++r) {
        int i = r * 256 + t;
        int e = base + i;
        if (e < nE) {
            int s = ei[e];
            s = min(max(s, 0), n - 1);
            int b = s >> 7;
            int lr = atomicAdd(&bcl[b], 1);
            tmp[i] = ((unsigned)b << 12) | (unsigned)lr | ((unsigned)(s & 127) << 21);
        }
    }
    __syncthreads();
    for (int i = t; i < NBUCK_MAX; i += 256) {
        int c = bcl[i];
        gbase[i] = c ? atomicAdd(&bcursor[i], c) : 0;
    }
    __syncthreads();
#pragma unroll
    for (int r = 0; r < CHUNK / 256; ++r) {
        int i = r * 256 + t;
        int e = base + i;
        if (e < nE) {
            unsigned u = tmp[i];
            int b = (u >> 12) & 0x1FF;
            int lr = u & 4095;
            int sl = (u >> 21) & 127;
            int d = ei[nE + e];
            d = min(max(d, 0), n - 1);
            int2 pr;
            pr.x = (d & 0xFFFF) | (sl << 16);
            pr.y = __float_as_int(edge_e[e]);
            binned[gbase[b] + lr] = pr;
        }
    }
}

// ---------------- K5: per-bucket node count + scan + scatter to CSR ----------------
__global__ __launch_bounds__(256) void k_sub(const int2* __restrict__ binned,
                                             const int* __restrict__ bcnt,
                                             const int* __restrict__ boffB,
                                             int* __restrict__ offs,
                                             int2* __restrict__ pairs, int n) {
    __shared__ int cnt_l[128];
    __shared__ int sA[128], sB[128];
    __shared__ int cur[128];
    int b = blockIdx.x;
    int t = threadIdx.x;
    int node0 = b << 7;
    if (t < 128) cnt_l[t] = 0;
    __syncthreads();
    int beg = boffB[b], c = bcnt[b];
    for (int i = t; i < c; i += 256) {
        int sl = (binned[beg + i].x >> 16) & 127;
        atomicAdd(&cnt_l[sl], 1);
    }
    __syncthreads();
    if (t < 128) sA[t] = cnt_l[t];
    __syncthreads();
    int *src = sA, *dst = sB;
    for (int ofs = 1; ofs < 128; ofs <<= 1) {
        if (t < 128) dst[t] = src[t] + (t >= ofs ? src[t - ofs] : 0);
        __syncthreads();
        int* tmp = src; src = dst; dst = tmp;
    }
    if (t < 128) {
        int ex = t ? src[t - 1] : 0;
        int node = node0 + t;
        if (node < n) offs[node] = beg + ex;
        cur[t] = ex;
    }
    __syncthreads();
    for (int i = t; i < c; i += 256) {
        int2 pr = binned[beg + i];
        int sl = (pr.x >> 16) & 127;
        int pos = beg + atomicAdd(&cur[sl], 1);
        int2 o;
        o.x = pr.x & 0xFFFF;
        o.y = pr.y;
        pairs[pos] = o;
    }
}

// ---------------- K6: per-node accumulation + finalize (elu), bf16 h gather ----------------
__global__ __launch_bounds__(256) void k_acc(const int2* __restrict__ pairs,
                                             const int* __restrict__ offs,
                                             const unsigned* __restrict__ hb,
                                             float* __restrict__ out, int n) {
    int wid = threadIdx.x >> 6, lane = threadIdx.x & 63;
    int node = blockIdx.x * 4 + wid;
    if (node >= n) return;
    int beg = offs[node], end = offs[node + 1];
    float ax = 0.f, ay = 0.f, rowsum = 0.f;
    int idx = beg;
    for (; idx + 8 <= end; idx += 8) {
        int2 p[8];
        unsigned u[8];
#pragma unroll
        for (int j = 0; j < 8; ++j) p[j] = pairs[idx + j];
#pragma unroll
        for (int j = 0; j < 8; ++j)
            u[j] = hb[(size_t)p[j].x * 64 + lane];
#pragma unroll
        for (int j = 0; j < 8; ++j) {
            float ee = __int_as_float(p[j].y);
            float hx = __uint_as_float(u[j] << 16);
            float hy = __uint_as_float(u[j] & 0xFFFF0000u);
            ax = fmaf(ee, hx, ax);
            ay = fmaf(ee, hy, ay);
            rowsum += ee;
        }
    }
    for (; idx < end; ++idx) {
        int2 p = pairs[idx];
        float ee = __int_as_float(p.y);
        unsigned u = hb[(size_t)p.x * 64 + lane];
        float hx = __uint_as_float(u << 16);
        float hy = __uint_as_float(u & 0xFFFF0000u);
        ax = fmaf(ee, hx, ax);
        ay = fmaf(ee, hy, ay);
        rowsum += ee;
    }
    float inv = 1.f / (rowsum + EPS);
    float x = ax * inv, y = ay * inv;
    x = x > 0.f ? x : (expf(x) - 1.f);
    y = y > 0.f ? y : (expf(y) - 1.f);
    float2 o = make_float2(x, y);
    *(float2*)&out[node * OUT_F + lane * 2] = o;
}

static inline size_t align_up(size_t v, size_t al) { return (v + al - 1) & ~(al - 1); }

extern "C" void kernel_launch(void* const* d_in, const int* in_sizes, int n_in,
                              void* d_out, int out_size, void* d_ws, size_t ws_size,
                              hipStream_t stream) {
    const float* input = (const float*)d_in[0];
    const int*   ei    = (const int*)d_in[1];
    const float* ew    = (const float*)d_in[2];
    const float* er    = (const float*)d_in[3];
    const float* W     = (const float*)d_in[4];
    const float* Wr    = (const float*)d_in[5];
    const float* a     = (const float*)d_in[6];
    float* out = (float*)d_out;

    const int n  = in_sizes[0] / IN_F;   // 50000
    const int nE = in_sizes[2];          // 1600000
    const int nbuck = (n + 127) >> 7;    // 391

    char* p = (char*)d_ws;
    size_t o = 0;
    unsigned* hb   = (unsigned*)(p + o); o = align_up(o + (size_t)n * 64 * 4, 256);
    float* hs      = (float*)(p + o); o = align_up(o + (size_t)n * 4, 256);
    float* hd      = (float*)(p + o); o = align_up(o + (size_t)n * 4, 256);
    float* edge_e  = (float*)(p + o); o = align_up(o + (size_t)nE * 4, 256);
    int*   offs    = (int*)(p + o);   o = align_up(o + (size_t)(n + 1) * 4, 256);
    int2*  pairs   = (int2*)(p + o);  o = align_up(o + (size_t)nE * 8, 256);
    int2*  binned  = (int2*)(p + o);  o = align_up(o + (size_t)nE * 8, 256);
    int*   bcnt    = (int*)(p + o);   o = align_up(o + NBUCK_MAX * 4, 256);
    int*   boffB   = (int*)(p + o);   o = align_up(o + NBUCK_MAX * 4, 256);
    int*   bcursor = (int*)(p + o);   o = align_up(o + NBUCK_MAX * 4, 256);
    (void)ws_size; (void)n_in; (void)out_size;

    hipMemsetAsync(bcnt, 0, NBUCK_MAX * 4, stream);

    k_gemm<<<(n + 127) / 128, 256, 0, stream>>>(input, W, a, hb, hs, hd, n);
    k_edge<<<1024, 256, 0, stream>>>(ei, ew, er, hs, hd, Wr, a, edge_e,
                                     bcnt, nE, n);
    k_scanB<<<1, 256, 0, stream>>>(bcnt, boffB, bcursor, offs, nbuck, n, nE);
    int nchunk = (nE + CHUNK - 1) / CHUNK;
    k_bin<<<nchunk, 256, 0, stream>>>(ei, edge_e, bcursor, binned, nE, n);
    k_sub<<<nbuck, 256, 0, stream>>>(binned, bcnt, boffB, offs, pairs, n);
    k_acc<<<(n + 3) / 4, 256, 0, stream>>>(pairs, offs, hb, out, n);
}

// Round 7
// 168.601 us; speedup vs baseline: 3.0098x; 1.2480x over previous
//
#include <hip/hip_runtime.h>

#define IN_F 256
#define OUT_F 128
#define ALPHA 0.2f
#define EPS 9e-15f
#define NBUCK_MAX 512      // ceil(n/128) = 391 for n = 50000
#define CHUNK 4096
#define LDST 40            // padded LDS row stride in ushorts (32 data + 8 pad)

typedef __attribute__((ext_vector_type(8))) short bf16x8;
typedef __attribute__((ext_vector_type(4))) float f32x4;

__device__ __forceinline__ unsigned bf16rnd(float f) {
    unsigned b = __float_as_uint(f);
    return b + 0x7FFFu + ((b >> 16) & 1u);   // take >>16 for the bf16 payload
}

// ---------------- K0: W (256x128 f32) -> Wt (bf16, [col][k] = [128][256]) ----------------
__global__ __launch_bounds__(256) void k_conv(const float* __restrict__ W,
                                              unsigned short* __restrict__ Wt) {
    int idx = blockIdx.x * 256 + threadIdx.x;
    if (idx < IN_F * OUT_F) {
        int k = idx >> 7, col = idx & 127;
        Wt[col * IN_F + k] = (unsigned short)(bf16rnd(W[idx]) >> 16);
    }
}

// ---------------- K1: h = input @ W via split-bf16 MFMA ----------------
// BM=128 rows/block, 4 waves x 32 rows, K in 8 steps of 32.
// acc = a_hi*b + a_lo*b (b = bf16-rounded W). Epilogue: bf16 h store + hs/hd dots.
__global__ __launch_bounds__(256) void k_gemm(const float* __restrict__ input,
                                              const unsigned short* __restrict__ Wt,
                                              const float* __restrict__ a,
                                              unsigned short* __restrict__ hb,  // [n][128] bf16
                                              float* __restrict__ hs,
                                              float* __restrict__ hd, int n) {
    __shared__ unsigned short Ah[128 * LDST];
    __shared__ unsigned short Al[128 * LDST];
    __shared__ unsigned short Bt[128 * LDST];

    const int t = threadIdx.x;
    const int lane = t & 63;
    const int wave = t >> 6;
    const int l15 = lane & 15;
    const int l4 = lane >> 4;
    const int row0 = blockIdx.x * 128;

    f32x4 acc[2][8];
#pragma unroll
    for (int rt = 0; rt < 2; ++rt)
#pragma unroll
        for (int ct = 0; ct < 8; ++ct) acc[rt][ct] = (f32x4)(0.f);

    for (int ks = 0; ks < 8; ++ks) {
        // ---- stage A (convert f32 -> hi/lo bf16) ----
#pragma unroll
        for (int c = t; c < 512; c += 256) {
            int row = c >> 2, kg = c & 3;
            int grow = row0 + row;
            float4 v0 = make_float4(0.f, 0.f, 0.f, 0.f);
            float4 v1 = v0;
            if (grow < n) {
                const float4* src = (const float4*)&input[(size_t)grow * IN_F + ks * 32 + kg * 8];
                v0 = src[0];
                v1 = src[1];
            }
            float xs[8] = {v0.x, v0.y, v0.z, v0.w, v1.x, v1.y, v1.z, v1.w};
            unsigned h[8], l[8];
#pragma unroll
            for (int j = 0; j < 8; ++j) {
                unsigned hbts = bf16rnd(xs[j]) >> 16;
                float hf = __uint_as_float(hbts << 16);
                unsigned lbts = bf16rnd(xs[j] - hf) >> 16;
                h[j] = hbts;
                l[j] = lbts;
            }
            uint4 ph = make_uint4(h[0] | (h[1] << 16), h[2] | (h[3] << 16),
                                  h[4] | (h[5] << 16), h[6] | (h[7] << 16));
            uint4 pl = make_uint4(l[0] | (l[1] << 16), l[2] | (l[3] << 16),
                                  l[4] | (l[5] << 16), l[6] | (l[7] << 16));
            *(uint4*)&Ah[row * LDST + kg * 8] = ph;
            *(uint4*)&Al[row * LDST + kg * 8] = pl;
        }
        // ---- stage B (copy pre-converted bf16 slice, [col][k]) ----
#pragma unroll
        for (int c = t; c < 512; c += 256) {
            int col = c >> 2, kg = c & 3;
            uint4 v = *(const uint4*)&Wt[col * IN_F + ks * 32 + kg * 8];
            *(uint4*)&Bt[col * LDST + kg * 8] = v;
        }
        __syncthreads();

        // ---- fragments + MFMA ----
        bf16x8 a_h[2], a_l[2];
#pragma unroll
        for (int rt = 0; rt < 2; ++rt) {
            int base = (wave * 32 + rt * 16 + l15) * LDST + l4 * 8;
            a_h[rt] = *(bf16x8*)&Ah[base];
            a_l[rt] = *(bf16x8*)&Al[base];
        }
#pragma unroll
        for (int ct = 0; ct < 8; ++ct) {
            bf16x8 b = *(bf16x8*)&Bt[(ct * 16 + l15) * LDST + l4 * 8];
            acc[0][ct] = __builtin_amdgcn_mfma_f32_16x16x32_bf16(a_h[0], b, acc[0][ct], 0, 0, 0);
            acc[0][ct] = __builtin_amdgcn_mfma_f32_16x16x32_bf16(a_l[0], b, acc[0][ct], 0, 0, 0);
            acc[1][ct] = __builtin_amdgcn_mfma_f32_16x16x32_bf16(a_h[1], b, acc[1][ct], 0, 0, 0);
            acc[1][ct] = __builtin_amdgcn_mfma_f32_16x16x32_bf16(a_l[1], b, acc[1][ct], 0, 0, 0);
        }
        __syncthreads();
    }

    // ---- epilogue: bf16 h store + fused hs/hd ----
    float as8[8], ad8[8];
#pragma unroll
    for (int ct = 0; ct < 8; ++ct) {
        as8[ct] = a[ct * 16 + l15];
        ad8[ct] = a[OUT_F + ct * 16 + l15];
    }
#pragma unroll
    for (int rt = 0; rt < 2; ++rt) {
#pragma unroll
        for (int r = 0; r < 4; ++r) {
            int grow = row0 + wave * 32 + rt * 16 + l4 * 4 + r;
            float ps = 0.f, pd = 0.f;
#pragma unroll
            for (int ct = 0; ct < 8; ++ct) {
                float v = acc[rt][ct][r];
                ps = fmaf(v, as8[ct], ps);
                pd = fmaf(v, ad8[ct], pd);
            }
#pragma unroll
            for (int o = 8; o; o >>= 1) {
                ps += __shfl_xor(ps, o);
                pd += __shfl_xor(pd, o);
            }
            if (grow < n) {
#pragma unroll
                for (int ct = 0; ct < 8; ++ct)
                    hb[(size_t)grow * OUT_F + ct * 16 + l15] =
                        (unsigned short)(bf16rnd(acc[rt][ct][r]) >> 16);
                if (l15 == 0) { hs[grow] = ps; hd[grow] = pd; }
            }
        }
    }
}

// ---------------- bucket scan: bcnt -> boffB (exclusive), init bcursor ----------------
__global__ __launch_bounds__(256) void k_scanB(const int* __restrict__ bcnt,
                                               int* __restrict__ boffB,
                                               int* __restrict__ bcursor,
                                               int* __restrict__ offs,
                                               int nbuck, int n, int nE) {
    __shared__ int sA[NBUCK_MAX], sB[NBUCK_MAX];
    int t = threadIdx.x;
    for (int i = t; i < NBUCK_MAX; i += 256) sA[i] = (i < nbuck) ? bcnt[i] : 0;
    __syncthreads();
    int *src = sA, *dst = sB;
    for (int ofs = 1; ofs < NBUCK_MAX; ofs <<= 1) {
        for (int i = t; i < NBUCK_MAX; i += 256)
            dst[i] = src[i] + (i >= ofs ? src[i - ofs] : 0);
        __syncthreads();
        int* tmp = src; src = dst; dst = tmp;
    }
    for (int i = t; i < nbuck; i += 256) {
        int ex = i ? src[i - 1] : 0;
        boffB[i] = ex;
        bcursor[i] = ex;
    }
    if (t == 0) offs[n] = nE;
}

// ---------------- K2: per-edge score -> edge_e, fused bucket histogram ----------------
__global__ __launch_bounds__(256) void k_edge(const int* __restrict__ ei,
                                              const float* __restrict__ ew,
                                              const float* __restrict__ er,
                                              const float* __restrict__ hs,
                                              const float* __restrict__ hd,
                                              const float* __restrict__ Wr,
                                              const float* __restrict__ a,
                                              float* __restrict__ edge_e,
                                              int* __restrict__ bcnt,
                                              int nE, int n) {
    __shared__ float war[8];
    __shared__ int bh[NBUCK_MAX];
    const int t = threadIdx.x;
    for (int i = t; i < NBUCK_MAX; i += 256) bh[i] = 0;
    {
        int rr = t >> 5;
        int l5 = t & 31;
        float p = 0.f;
#pragma unroll
        for (int k = 0; k < 4; ++k)
            p = fmaf(Wr[rr * OUT_F + l5 * 4 + k], a[2 * OUT_F + l5 * 4 + k], p);
#pragma unroll
        for (int o = 16; o; o >>= 1) p += __shfl_xor(p, o, 32);
        if (l5 == 0) war[rr] = p;
    }
    __syncthreads();

    float aw = a[3 * OUT_F];
    int stride = gridDim.x * 256;
    for (int e = blockIdx.x * 256 + t; e < nE; e += stride) {
        int s = ei[e], d = ei[nE + e];
        s = min(max(s, 0), n - 1);
        d = min(max(d, 0), n - 1);
        float4 r0 = *(const float4*)&er[(size_t)e * 8];
        float4 r1 = *(const float4*)&er[(size_t)e * 8 + 4];
        float sc = hs[s] + hd[d]
                 + r0.x * war[0] + r0.y * war[1] + r0.z * war[2] + r0.w * war[3]
                 + r1.x * war[4] + r1.y * war[5] + r1.z * war[6] + r1.w * war[7]
                 + aw * ew[e];
        float lr = sc > 0.f ? sc : ALPHA * sc;
        edge_e[e] = expf(-lr);
        atomicAdd(&bh[s >> 7], 1);
    }
    __syncthreads();
    int nbuck = (n + 127) >> 7;
    for (int i = t; i < nbuck; i += 256)
        if (bh[i]) atomicAdd(&bcnt[i], bh[i]);
}

// ---------------- K4: binned coarse scatter ----------------
// tmp word: [0:12)=local rank, [12:21)=bucket, [21:28)=s&127
__global__ __launch_bounds__(256) void k_bin(const int* __restrict__ ei,
                                             const float* __restrict__ edge_e,
                                             int* __restrict__ bcursor,
                                             int2* __restrict__ binned,
                                             int nE, int n) {
    __shared__ int bcl[NBUCK_MAX];
    __shared__ int gbase[NBUCK_MAX];
    __shared__ unsigned int tmp[CHUNK];
    const int t = threadIdx.x;
    const int base = blockIdx.x * CHUNK;
    for (int i = t; i < NBUCK_MAX; i += 256) bcl[i] = 0;
    __syncthreads();
#pragma unroll
    for (int r = 0; r < CHUNK / 256; ++r) {
        int i = r * 256 + t;
        int e = base + i;
        if (e < nE) {
            int s = ei[e];
            s = min(max(s, 0), n - 1);
            int b = s >> 7;
            int lr = atomicAdd(&bcl[b], 1);
            tmp[i] = ((unsigned)b << 12) | (unsigned)lr | ((unsigned)(s & 127) << 21);
        }
    }
    __syncthreads();
    for (int i = t; i < NBUCK_MAX; i += 256) {
        int c = bcl[i];
        gbase[i] = c ? atomicAdd(&bcursor[i], c) : 0;
    }
    __syncthreads();
#pragma unroll
    for (int r = 0; r < CHUNK / 256; ++r) {
        int i = r * 256 + t;
        int e = base + i;
        if (e < nE) {
            unsigned u = tmp[i];
            int b = (u >> 12) & 0x1FF;
            int lr = u & 4095;
            int sl = (u >> 21) & 127;
            int d = ei[nE + e];
            d = min(max(d, 0), n - 1);
            int2 pr;
            pr.x = (d & 0xFFFF) | (sl << 16);
            pr.y = __float_as_int(edge_e[e]);
            binned[gbase[b] + lr] = pr;
        }
    }
}

// ---------------- K5: per-bucket node count + scan + scatter to CSR ----------------
__global__ __launch_bounds__(256) void k_sub(const int2* __restrict__ binned,
                                             const int* __restrict__ bcnt,
                                             const int* __restrict__ boffB,
                                             int* __restrict__ offs,
                                             int2* __restrict__ pairs, int n) {
    __shared__ int cnt_l[128];
    __shared__ int sA[128], sB[128];
    __shared__ int cur[128];
    int b = blockIdx.x;
    int t = threadIdx.x;
    int node0 = b << 7;
    if (t < 128) cnt_l[t] = 0;
    __syncthreads();
    int beg = boffB[b], c = bcnt[b];
    for (int i = t; i < c; i += 256) {
        int sl = (binned[beg + i].x >> 16) & 127;
        atomicAdd(&cnt_l[sl], 1);
    }
    __syncthreads();
    if (t < 128) sA[t] = cnt_l[t];
    __syncthreads();
    int *src = sA, *dst = sB;
    for (int ofs = 1; ofs < 128; ofs <<= 1) {
        if (t < 128) dst[t] = src[t] + (t >= ofs ? src[t - ofs] : 0);
        __syncthreads();
        int* tmp = src; src = dst; dst = tmp;
    }
    if (t < 128) {
        int ex = t ? src[t - 1] : 0;
        int node = node0 + t;
        if (node < n) offs[node] = beg + ex;
        cur[t] = ex;
    }
    __syncthreads();
    for (int i = t; i < c; i += 256) {
        int2 pr = binned[beg + i];
        int sl = (pr.x >> 16) & 127;
        int pos = beg + atomicAdd(&cur[sl], 1);
        int2 o;
        o.x = pr.x & 0xFFFF;
        o.y = pr.y;
        pairs[pos] = o;
    }
}

// ---------------- K6: per-node accumulation + finalize (elu), bf16 h gather ----------------
__global__ __launch_bounds__(256) void k_acc(const int2* __restrict__ pairs,
                                             const int* __restrict__ offs,
                                             const unsigned* __restrict__ hb,
                                             float* __restrict__ out, int n) {
    int wid = threadIdx.x >> 6, lane = threadIdx.x & 63;
    int node = blockIdx.x * 4 + wid;
    if (node >= n) return;
    int beg = offs[node], end = offs[node + 1];
    float ax = 0.f, ay = 0.f, rowsum = 0.f;
    int idx = beg;
    for (; idx + 8 <= end; idx += 8) {
        int2 p[8];
        unsigned u[8];
#pragma unroll
        for (int j = 0; j < 8; ++j) p[j] = pairs[idx + j];
#pragma unroll
        for (int j = 0; j < 8; ++j)
            u[j] = hb[(size_t)p[j].x * 64 + lane];
#pragma unroll
        for (int j = 0; j < 8; ++j) {
            float ee = __int_as_float(p[j].y);
            float hx = __uint_as_float(u[j] << 16);
            float hy = __uint_as_float(u[j] & 0xFFFF0000u);
            ax = fmaf(ee, hx, ax);
            ay = fmaf(ee, hy, ay);
            rowsum += ee;
        }
    }
    for (; idx < end; ++idx) {
        int2 p = pairs[idx];
        float ee = __int_as_float(p.y);
        unsigned u = hb[(size_t)p.x * 64 + lane];
        float hx = __uint_as_float(u << 16);
        float hy = __uint_as_float(u & 0xFFFF0000u);
        ax = fmaf(ee, hx, ax);
        ay = fmaf(ee, hy, ay);
        rowsum += ee;
    }
    float inv = 1.f / (rowsum + EPS);
    float x = ax * inv, y = ay * inv;
    x = x > 0.f ? x : (expf(x) - 1.f);
    y = y > 0.f ? y : (expf(y) - 1.f);
    float2 o = make_float2(x, y);
    *(float2*)&out[node * OUT_F + lane * 2] = o;
}

static inline size_t align_up(size_t v, size_t al) { return (v + al - 1) & ~(al - 1); }

extern "C" void kernel_launch(void* const* d_in, const int* in_sizes, int n_in,
                              void* d_out, int out_size, void* d_ws, size_t ws_size,
                              hipStream_t stream) {
    const float* input = (const float*)d_in[0];
    const int*   ei    = (const int*)d_in[1];
    const float* ew    = (const float*)d_in[2];
    const float* er    = (const float*)d_in[3];
    const float* W     = (const float*)d_in[4];
    const float* Wr    = (const float*)d_in[5];
    const float* a     = (const float*)d_in[6];
    float* out = (float*)d_out;

    const int n  = in_sizes[0] / IN_F;   // 50000
    const int nE = in_sizes[2];          // 1600000
    const int nbuck = (n + 127) >> 7;    // 391

    char* p = (char*)d_ws;
    size_t o = 0;
    unsigned short* hb = (unsigned short*)(p + o); o = align_up(o + (size_t)n * OUT_F * 2, 256);
    unsigned short* Wt = (unsigned short*)(p + o); o = align_up(o + (size_t)IN_F * OUT_F * 2, 256);
    float* hs      = (float*)(p + o); o = align_up(o + (size_t)n * 4, 256);
    float* hd      = (float*)(p + o); o = align_up(o + (size_t)n * 4, 256);
    float* edge_e  = (float*)(p + o); o = align_up(o + (size_t)nE * 4, 256);
    int*   offs    = (int*)(p + o);   o = align_up(o + (size_t)(n + 1) * 4, 256);
    int2*  pairs   = (int2*)(p + o);  o = align_up(o + (size_t)nE * 8, 256);
    int2*  binned  = (int2*)(p + o);  o = align_up(o + (size_t)nE * 8, 256);
    int*   bcnt    = (int*)(p + o);   o = align_up(o + NBUCK_MAX * 4, 256);
    int*   boffB   = (int*)(p + o);   o = align_up(o + NBUCK_MAX * 4, 256);
    int*   bcursor = (int*)(p + o);   o = align_up(o + NBUCK_MAX * 4, 256);
    (void)ws_size; (void)n_in; (void)out_size;

    (void)hipMemsetAsync(bcnt, 0, NBUCK_MAX * 4, stream);

    k_conv<<<(IN_F * OUT_F + 255) / 256, 256, 0, stream>>>(W, Wt);
    k_gemm<<<(n + 127) / 128, 256, 0, stream>>>(input, Wt, a, hb, hs, hd, n);
    k_edge<<<1024, 256, 0, stream>>>(ei, ew, er, hs, hd, Wr, a, edge_e,
                                     bcnt, nE, n);
    k_scanB<<<1, 256, 0, stream>>>(bcnt, boffB, bcursor, offs, nbuck, n, nE);
    int nchunk = (nE + CHUNK - 1) / CHUNK;
    k_bin<<<nchunk, 256, 0, stream>>>(ei, edge_e, bcursor, binned, nE, n);
    k_sub<<<nbuck, 256, 0, stream>>>(binned, bcnt, boffB, offs, pairs, n);
    k_acc<<<(n + 3) / 4, 256, 0, stream>>>(pairs, offs, (const unsigned*)hb, out, n);
}

// Round 8
// 164.489 us; speedup vs baseline: 3.0850x; 1.0250x over previous
//
#include <hip/hip_runtime.h>

#define IN_F 256
#define OUT_F 128
#define ALPHA 0.2f
#define EPS 9e-15f
#define NBUCK_MAX 512      // ceil(n/128) = 391 for n = 50000
#define CHUNK 4096
#define LDST 40            // padded LDS row stride in ushorts (32 data + 8 pad)

typedef __attribute__((ext_vector_type(8))) short bf16x8;
typedef __attribute__((ext_vector_type(4))) float f32x4;

__device__ __forceinline__ unsigned bf16rnd(float f) {
    unsigned b = __float_as_uint(f);
    return b + 0x7FFFu + ((b >> 16) & 1u);   // take >>16 for the bf16 payload
}

// ---------------- K0: W (256x128 f32) -> Wt (bf16, [col][k] = [128][256]) ----------------
__global__ __launch_bounds__(256) void k_conv(const float* __restrict__ W,
                                              unsigned short* __restrict__ Wt) {
    int idx = blockIdx.x * 256 + threadIdx.x;
    if (idx < IN_F * OUT_F) {
        int k = idx >> 7, col = idx & 127;
        Wt[col * IN_F + k] = (unsigned short)(bf16rnd(W[idx]) >> 16);
    }
}

// ---------------- K1: h = input @ W via split-bf16 MFMA ----------------
__global__ __launch_bounds__(256) void k_gemm(const float* __restrict__ input,
                                              const unsigned short* __restrict__ Wt,
                                              const float* __restrict__ a,
                                              unsigned short* __restrict__ hb,  // [n][128] bf16
                                              float* __restrict__ hs,
                                              float* __restrict__ hd, int n) {
    __shared__ unsigned short Ah[128 * LDST];
    __shared__ unsigned short Al[128 * LDST];
    __shared__ unsigned short Bt[128 * LDST];

    const int t = threadIdx.x;
    const int lane = t & 63;
    const int wave = t >> 6;
    const int l15 = lane & 15;
    const int l4 = lane >> 4;
    const int row0 = blockIdx.x * 128;

    f32x4 acc[2][8];
#pragma unroll
    for (int rt = 0; rt < 2; ++rt)
#pragma unroll
        for (int ct = 0; ct < 8; ++ct) acc[rt][ct] = (f32x4)(0.f);

    for (int ks = 0; ks < 8; ++ks) {
        // ---- stage A (convert f32 -> hi/lo bf16) ----
#pragma unroll
        for (int c = t; c < 512; c += 256) {
            int row = c >> 2, kg = c & 3;
            int grow = row0 + row;
            float4 v0 = make_float4(0.f, 0.f, 0.f, 0.f);
            float4 v1 = v0;
            if (grow < n) {
                const float4* src = (const float4*)&input[(size_t)grow * IN_F + ks * 32 + kg * 8];
                v0 = src[0];
                v1 = src[1];
            }
            float xs[8] = {v0.x, v0.y, v0.z, v0.w, v1.x, v1.y, v1.z, v1.w};
            unsigned h[8], l[8];
#pragma unroll
            for (int j = 0; j < 8; ++j) {
                unsigned hbts = bf16rnd(xs[j]) >> 16;
                float hf = __uint_as_float(hbts << 16);
                unsigned lbts = bf16rnd(xs[j] - hf) >> 16;
                h[j] = hbts;
                l[j] = lbts;
            }
            uint4 ph = make_uint4(h[0] | (h[1] << 16), h[2] | (h[3] << 16),
                                  h[4] | (h[5] << 16), h[6] | (h[7] << 16));
            uint4 pl = make_uint4(l[0] | (l[1] << 16), l[2] | (l[3] << 16),
                                  l[4] | (l[5] << 16), l[6] | (l[7] << 16));
            *(uint4*)&Ah[row * LDST + kg * 8] = ph;
            *(uint4*)&Al[row * LDST + kg * 8] = pl;
        }
        // ---- stage B ----
#pragma unroll
        for (int c = t; c < 512; c += 256) {
            int col = c >> 2, kg = c & 3;
            uint4 v = *(const uint4*)&Wt[col * IN_F + ks * 32 + kg * 8];
            *(uint4*)&Bt[col * LDST + kg * 8] = v;
        }
        __syncthreads();

        bf16x8 a_h[2], a_l[2];
#pragma unroll
        for (int rt = 0; rt < 2; ++rt) {
            int base = (wave * 32 + rt * 16 + l15) * LDST + l4 * 8;
            a_h[rt] = *(bf16x8*)&Ah[base];
            a_l[rt] = *(bf16x8*)&Al[base];
        }
#pragma unroll
        for (int ct = 0; ct < 8; ++ct) {
            bf16x8 b = *(bf16x8*)&Bt[(ct * 16 + l15) * LDST + l4 * 8];
            acc[0][ct] = __builtin_amdgcn_mfma_f32_16x16x32_bf16(a_h[0], b, acc[0][ct], 0, 0, 0);
            acc[0][ct] = __builtin_amdgcn_mfma_f32_16x16x32_bf16(a_l[0], b, acc[0][ct], 0, 0, 0);
            acc[1][ct] = __builtin_amdgcn_mfma_f32_16x16x32_bf16(a_h[1], b, acc[1][ct], 0, 0, 0);
            acc[1][ct] = __builtin_amdgcn_mfma_f32_16x16x32_bf16(a_l[1], b, acc[1][ct], 0, 0, 0);
        }
        __syncthreads();
    }

    float as8[8], ad8[8];
#pragma unroll
    for (int ct = 0; ct < 8; ++ct) {
        as8[ct] = a[ct * 16 + l15];
        ad8[ct] = a[OUT_F + ct * 16 + l15];
    }
#pragma unroll
    for (int rt = 0; rt < 2; ++rt) {
#pragma unroll
        for (int r = 0; r < 4; ++r) {
            int grow = row0 + wave * 32 + rt * 16 + l4 * 4 + r;
            float ps = 0.f, pd = 0.f;
#pragma unroll
            for (int ct = 0; ct < 8; ++ct) {
                float v = acc[rt][ct][r];
                ps = fmaf(v, as8[ct], ps);
                pd = fmaf(v, ad8[ct], pd);
            }
#pragma unroll
            for (int o = 8; o; o >>= 1) {
                ps += __shfl_xor(ps, o);
                pd += __shfl_xor(pd, o);
            }
            if (grow < n) {
#pragma unroll
                for (int ct = 0; ct < 8; ++ct)
                    hb[(size_t)grow * OUT_F + ct * 16 + l15] =
                        (unsigned short)(bf16rnd(acc[rt][ct][r]) >> 16);
                if (l15 == 0) { hs[grow] = ps; hd[grow] = pd; }
            }
        }
    }
}

// ---------------- K2: bucket histogram only (one cheap pass over ei src) ----------------
__global__ __launch_bounds__(256) void k_histB(const int* __restrict__ ei,
                                               int* __restrict__ bcnt,
                                               int nE, int n) {
    __shared__ int bh[NBUCK_MAX];
    const int t = threadIdx.x;
    for (int i = t; i < NBUCK_MAX; i += 256) bh[i] = 0;
    __syncthreads();
    int stride = gridDim.x * 256;
    for (int e = blockIdx.x * 256 + t; e < nE; e += stride) {
        int s = ei[e];
        s = min(max(s, 0), n - 1);
        atomicAdd(&bh[s >> 7], 1);
    }
    __syncthreads();
    int nbuck = (n + 127) >> 7;
    for (int i = t; i < nbuck; i += 256)
        if (bh[i]) atomicAdd(&bcnt[i], bh[i]);
}

// ---------------- bucket scan: bcnt -> boffB (exclusive), init bcursor ----------------
__global__ __launch_bounds__(256) void k_scanB(const int* __restrict__ bcnt,
                                               int* __restrict__ boffB,
                                               int* __restrict__ bcursor,
                                               int* __restrict__ offs,
                                               int nbuck, int n, int nE) {
    __shared__ int sA[NBUCK_MAX], sB[NBUCK_MAX];
    int t = threadIdx.x;
    for (int i = t; i < NBUCK_MAX; i += 256) sA[i] = (i < nbuck) ? bcnt[i] : 0;
    __syncthreads();
    int *src = sA, *dst = sB;
    for (int ofs = 1; ofs < NBUCK_MAX; ofs <<= 1) {
        for (int i = t; i < NBUCK_MAX; i += 256)
            dst[i] = src[i] + (i >= ofs ? src[i - ofs] : 0);
        __syncthreads();
        int* tmp = src; src = dst; dst = tmp;
    }
    for (int i = t; i < nbuck; i += 256) {
        int ex = i ? src[i - 1] : 0;
        boffB[i] = ex;
        bcursor[i] = ex;
    }
    if (t == 0) offs[n] = nE;
}

// ---------------- K3: FUSED per-edge score + binned scatter ----------------
// Per 4096-edge chunk: compute ee, LDS-rank by bucket, reserve global ranges,
// write (dst | sl<<16, ee) records contiguously per bucket.
// tmp word: [0:12)=local rank, [12:21)=bucket, [21:28)=s&127
__global__ __launch_bounds__(256) void k_edgebin(const int* __restrict__ ei,
                                                 const float* __restrict__ ew,
                                                 const float* __restrict__ er,
                                                 const float* __restrict__ hs,
                                                 const float* __restrict__ hd,
                                                 const float* __restrict__ Wr,
                                                 const float* __restrict__ a,
                                                 int* __restrict__ bcursor,
                                                 int2* __restrict__ binned,
                                                 int nE, int n) {
    __shared__ float war[8];
    __shared__ int bcl[NBUCK_MAX];
    __shared__ int gbase[NBUCK_MAX];
    __shared__ unsigned int tmp[CHUNK];
    __shared__ float tmp_ee[CHUNK];
    __shared__ unsigned short tmp_d[CHUNK];
    const int t = threadIdx.x;
    const int base = blockIdx.x * CHUNK;
    for (int i = t; i < NBUCK_MAX; i += 256) bcl[i] = 0;
    {
        int rr = t >> 5;
        int l5 = t & 31;
        float p = 0.f;
#pragma unroll
        for (int k = 0; k < 4; ++k)
            p = fmaf(Wr[rr * OUT_F + l5 * 4 + k], a[2 * OUT_F + l5 * 4 + k], p);
#pragma unroll
        for (int o = 16; o; o >>= 1) p += __shfl_xor(p, o, 32);
        if (l5 == 0) war[rr] = p;
    }
    __syncthreads();

    const float aw = a[3 * OUT_F];
#pragma unroll
    for (int r = 0; r < CHUNK / 256; ++r) {
        int i = r * 256 + t;
        int e = base + i;
        if (e < nE) {
            int s = ei[e], d = ei[nE + e];
            s = min(max(s, 0), n - 1);
            d = min(max(d, 0), n - 1);
            float4 r0 = *(const float4*)&er[(size_t)e * 8];
            float4 r1 = *(const float4*)&er[(size_t)e * 8 + 4];
            float sc = hs[s] + hd[d]
                     + r0.x * war[0] + r0.y * war[1] + r0.z * war[2] + r0.w * war[3]
                     + r1.x * war[4] + r1.y * war[5] + r1.z * war[6] + r1.w * war[7]
                     + aw * ew[e];
            float lr = sc > 0.f ? sc : ALPHA * sc;
            int b = s >> 7;
            int rank = atomicAdd(&bcl[b], 1);
            tmp[i] = ((unsigned)b << 12) | (unsigned)rank | ((unsigned)(s & 127) << 21);
            tmp_ee[i] = expf(-lr);
            tmp_d[i] = (unsigned short)d;
        }
    }
    __syncthreads();
    for (int i = t; i < NBUCK_MAX; i += 256) {
        int c = bcl[i];
        gbase[i] = c ? atomicAdd(&bcursor[i], c) : 0;
    }
    __syncthreads();
#pragma unroll
    for (int r = 0; r < CHUNK / 256; ++r) {
        int i = r * 256 + t;
        int e = base + i;
        if (e < nE) {
            unsigned u = tmp[i];
            int b = (u >> 12) & 0x1FF;
            int rank = u & 4095;
            int sl = (u >> 21) & 127;
            int2 pr;
            pr.x = (int)tmp_d[i] | (sl << 16);
            pr.y = __float_as_int(tmp_ee[i]);
            binned[gbase[b] + rank] = pr;
        }
    }
}

// ---------------- K5: per-bucket node count + scan + scatter to CSR ----------------
__global__ __launch_bounds__(256) void k_sub(const int2* __restrict__ binned,
                                             const int* __restrict__ bcnt,
                                             const int* __restrict__ boffB,
                                             int* __restrict__ offs,
                                             int2* __restrict__ pairs, int n) {
    __shared__ int cnt_l[128];
    __shared__ int sA[128], sB[128];
    __shared__ int cur[128];
    int b = blockIdx.x;
    int t = threadIdx.x;
    int node0 = b << 7;
    if (t < 128) cnt_l[t] = 0;
    __syncthreads();
    int beg = boffB[b], c = bcnt[b];
    for (int i = t; i < c; i += 256) {
        int sl = (binned[beg + i].x >> 16) & 127;
        atomicAdd(&cnt_l[sl], 1);
    }
    __syncthreads();
    if (t < 128) sA[t] = cnt_l[t];
    __syncthreads();
    int *src = sA, *dst = sB;
    for (int ofs = 1; ofs < 128; ofs <<= 1) {
        if (t < 128) dst[t] = src[t] + (t >= ofs ? src[t - ofs] : 0);
        __syncthreads();
        int* tmp = src; src = dst; dst = tmp;
    }
    if (t < 128) {
        int ex = t ? src[t - 1] : 0;
        int node = node0 + t;
        if (node < n) offs[node] = beg + ex;
        cur[t] = ex;
    }
    __syncthreads();
    for (int i = t; i < c; i += 256) {
        int2 pr = binned[beg + i];
        int sl = (pr.x >> 16) & 127;
        int pos = beg + atomicAdd(&cur[sl], 1);
        int2 o;
        o.x = pr.x & 0xFFFF;
        o.y = pr.y;
        pairs[pos] = o;
    }
}

// ---------------- K6: per-node accumulation + finalize (elu), bf16 h gather ----------------
__global__ __launch_bounds__(256) void k_acc(const int2* __restrict__ pairs,
                                             const int* __restrict__ offs,
                                             const unsigned* __restrict__ hb,
                                             float* __restrict__ out, int n) {
    int wid = threadIdx.x >> 6, lane = threadIdx.x & 63;
    int node = blockIdx.x * 4 + wid;
    if (node >= n) return;
    int beg = offs[node], end = offs[node + 1];
    float ax = 0.f, ay = 0.f, rowsum = 0.f;
    int idx = beg;
    for (; idx + 8 <= end; idx += 8) {
        int2 p[8];
        unsigned u[8];
#pragma unroll
        for (int j = 0; j < 8; ++j) p[j] = pairs[idx + j];
#pragma unroll
        for (int j = 0; j < 8; ++j)
            u[j] = hb[(size_t)p[j].x * 64 + lane];
#pragma unroll
        for (int j = 0; j < 8; ++j) {
            float ee = __int_as_float(p[j].y);
            float hx = __uint_as_float(u[j] << 16);
            float hy = __uint_as_float(u[j] & 0xFFFF0000u);
            ax = fmaf(ee, hx, ax);
            ay = fmaf(ee, hy, ay);
            rowsum += ee;
        }
    }
    for (; idx < end; ++idx) {
        int2 p = pairs[idx];
        float ee = __int_as_float(p.y);
        unsigned u = hb[(size_t)p.x * 64 + lane];
        float hx = __uint_as_float(u << 16);
        float hy = __uint_as_float(u & 0xFFFF0000u);
        ax = fmaf(ee, hx, ax);
        ay = fmaf(ee, hy, ay);
        rowsum += ee;
    }
    float inv = 1.f / (rowsum + EPS);
    float x = ax * inv, y = ay * inv;
    x = x > 0.f ? x : (expf(x) - 1.f);
    y = y > 0.f ? y : (expf(y) - 1.f);
    float2 o = make_float2(x, y);
    *(float2*)&out[node * OUT_F + lane * 2] = o;
}

static inline size_t align_up(size_t v, size_t al) { return (v + al - 1) & ~(al - 1); }

extern "C" void kernel_launch(void* const* d_in, const int* in_sizes, int n_in,
                              void* d_out, int out_size, void* d_ws, size_t ws_size,
                              hipStream_t stream) {
    const float* input = (const float*)d_in[0];
    const int*   ei    = (const int*)d_in[1];
    const float* ew    = (const float*)d_in[2];
    const float* er    = (const float*)d_in[3];
    const float* W     = (const float*)d_in[4];
    const float* Wr    = (const float*)d_in[5];
    const float* a     = (const float*)d_in[6];
    float* out = (float*)d_out;

    const int n  = in_sizes[0] / IN_F;   // 50000
    const int nE = in_sizes[2];          // 1600000
    const int nbuck = (n + 127) >> 7;    // 391

    char* p = (char*)d_ws;
    size_t o = 0;
    unsigned short* hb = (unsigned short*)(p + o); o = align_up(o + (size_t)n * OUT_F * 2, 256);
    unsigned short* Wt = (unsigned short*)(p + o); o = align_up(o + (size_t)IN_F * OUT_F * 2, 256);
    float* hs      = (float*)(p + o); o = align_up(o + (size_t)n * 4, 256);
    float* hd      = (float*)(p + o); o = align_up(o + (size_t)n * 4, 256);
    int*   offs    = (int*)(p + o);   o = align_up(o + (size_t)(n + 1) * 4, 256);
    int2*  pairs   = (int2*)(p + o);  o = align_up(o + (size_t)nE * 8, 256);
    int2*  binned  = (int2*)(p + o);  o = align_up(o + (size_t)nE * 8, 256);
    int*   bcnt    = (int*)(p + o);   o = align_up(o + NBUCK_MAX * 4, 256);
    int*   boffB   = (int*)(p + o);   o = align_up(o + NBUCK_MAX * 4, 256);
    int*   bcursor = (int*)(p + o);   o = align_up(o + NBUCK_MAX * 4, 256);
    (void)ws_size; (void)n_in; (void)out_size;

    (void)hipMemsetAsync(bcnt, 0, NBUCK_MAX * 4, stream);

    k_conv<<<(IN_F * OUT_F + 255) / 256, 256, 0, stream>>>(W, Wt);
    k_gemm<<<(n + 127) / 128, 256, 0, stream>>>(input, Wt, a, hb, hs, hd, n);
    k_histB<<<1024, 256, 0, stream>>>(ei, bcnt, nE, n);
    k_scanB<<<1, 256, 0, stream>>>(bcnt, boffB, bcursor, offs, nbuck, n, nE);
    int nchunk = (nE + CHUNK - 1) / CHUNK;
    k_edgebin<<<nchunk, 256, 0, stream>>>(ei, ew, er, hs, hd, Wr, a,
                                          bcursor, binned, nE, n);
    k_sub<<<nbuck, 256, 0, stream>>>(binned, bcnt, boffB, offs, pairs, n);
    k_acc<<<(n + 3) / 4, 256, 0, stream>>>(pairs, offs, (const unsigned*)hb, out, n);
}